// Round 5
// baseline (816.098 us; speedup 1.0000x reference)
//
#include <hip/hip_runtime.h>
#include <math.h>

#define NB 4
#define NC 96
#define NH 128
#define NW 128
#define HWSZ (NH * NW)          // 16384
#define NK 9
#define AUXC 27                 // 18 offset + 9 mask channels
#define CKK (NC * NK)           // 864
#define WT_STRIDE 28            // 27 outputs + 1 pad
#define WT_ELEMS (CKK * WT_STRIDE)      // 24192
#define WB_ELEMS (NC * CKK)             // 82944 bf16 deform weights

typedef __attribute__((ext_vector_type(8))) short bf16x8;
typedef __attribute__((ext_vector_type(4))) float f32x4;

__device__ __forceinline__ unsigned int bf16r(float f) {
    unsigned int u = __float_as_uint(f);
    u += 0x7fffu + ((u >> 16) & 1u);
    return u >> 16;                      // RNE bf16 bits
}

// ---------------------------------------------------------------------------
// Kernel 0: weight prep.
//   wT[(c*9+tap)*28 + oc]  (fp32, conv27)
//   wb16[oc*864 + c*9 + k] (bf16 bits, deform MFMA A)
// ---------------------------------------------------------------------------
__global__ __launch_bounds__(256) void prep_weights_kernel(
    const float* __restrict__ offw, const float* __restrict__ modw,
    const float* __restrict__ w,
    float* __restrict__ wT, unsigned short* __restrict__ wb16)
{
    int idx = blockIdx.x * 256 + threadIdx.x;
    if (idx < WT_ELEMS) {
        int row = idx / WT_STRIDE;          // c*9+tap
        int col = idx - row * WT_STRIDE;    // oc
        float v = 0.f;
        if (col < 18)      v = offw[col * CKK + row];
        else if (col < 27) v = modw[(col - 18) * CKK + row];
        wT[idx] = v;
    }
    int j = idx - WT_ELEMS;
    if (j >= 0 && j < WB_ELEMS) {
        wb16[j] = (unsigned short)bf16r(w[j]);
    }
}

// ---------------------------------------------------------------------------
// Kernel 0b: f32 -> bf16 plane conversion (for deform sampling source)
// ---------------------------------------------------------------------------
__global__ __launch_bounds__(256) void tobf16_kernel(
    const float* __restrict__ in, unsigned short* __restrict__ o)
{
    const int n4 = NB * NC * HWSZ / 4;
    for (int i = blockIdx.x * 256 + threadIdx.x; i < n4; i += gridDim.x * 256) {
        float4 v = ((const float4*)in)[i];
        ushort4 u;
        u.x = (unsigned short)bf16r(v.x);
        u.y = (unsigned short)bf16r(v.y);
        u.z = (unsigned short)bf16r(v.z);
        u.w = (unsigned short)bf16r(v.w);
        ((ushort4*)o)[i] = u;
    }
}

// ---------------------------------------------------------------------------
// Kernel 1: 3x3 conv -> 18 offset + 9 mask (2*sigmoid). (unchanged, fp32)
// ---------------------------------------------------------------------------
__global__ __launch_bounds__(512) void conv27_kernel(
    const float* __restrict__ in,
    const float* __restrict__ wT,
    const float* __restrict__ offb, const float* __restrict__ modb,
    float* __restrict__ aux)
{
    __shared__ float red[3][AUXC][NW];      // 41472 B

    int t  = threadIdx.x;
    int px = t & 127;
    int g  = t >> 7;
    int b  = blockIdx.x >> 7;
    int y  = blockIdx.x & 127;

    const bool hasT = (y > 0), hasB = (y < NH - 1);   // uniform
    const int offT = hasT ? NW : 0;
    const int offB = hasB ? NW : 0;
    int pxl = px > 0 ? px - 1 : 0;
    int pxr = px < NW - 1 ? px + 1 : NW - 1;
    const float mL = (px == 0) ? 0.f : 1.f;
    const float mR = (px == NW - 1) ? 0.f : 1.f;

    float acc[AUXC];
#pragma unroll
    for (int i = 0; i < AUXC; ++i) acc[i] = 0.f;

    const float* imgb = in + (size_t)b * NC * HWSZ + y * NW;
    int c0 = g * 24;

    for (int c = c0; c < c0 + 24; ++c) {
        const float* rm = imgb + c * HWSZ;
        const float* rt = rm - offT;
        const float* rb = rm + offB;
        float t0 = rt[pxl], t1 = rt[px], t2 = rt[pxr];
        float t3 = rm[pxl], t4 = rm[px], t5 = rm[pxr];
        float t6 = rb[pxl], t7 = rb[px], t8 = rb[pxr];
        if (!hasT) { t0 = 0.f; t1 = 0.f; t2 = 0.f; }
        if (!hasB) { t6 = 0.f; t7 = 0.f; t8 = 0.f; }
        t0 *= mL; t3 *= mL; t6 *= mL;
        t2 *= mR; t5 *= mR; t8 *= mR;

        const float* wb = wT + c * NK * WT_STRIDE;     // uniform -> s_loads
#pragma unroll
        for (int oc = 0; oc < AUXC; ++oc) {
            float a = acc[oc];
            a = fmaf(t0, wb[0 * WT_STRIDE + oc], a);
            a = fmaf(t1, wb[1 * WT_STRIDE + oc], a);
            a = fmaf(t2, wb[2 * WT_STRIDE + oc], a);
            a = fmaf(t3, wb[3 * WT_STRIDE + oc], a);
            a = fmaf(t4, wb[4 * WT_STRIDE + oc], a);
            a = fmaf(t5, wb[5 * WT_STRIDE + oc], a);
            a = fmaf(t6, wb[6 * WT_STRIDE + oc], a);
            a = fmaf(t7, wb[7 * WT_STRIDE + oc], a);
            a = fmaf(t8, wb[8 * WT_STRIDE + oc], a);
            acc[oc] = a;
        }
    }

    if (g > 0) {
#pragma unroll
        for (int oc = 0; oc < AUXC; ++oc) red[g - 1][oc][px] = acc[oc];
    }
    __syncthreads();
    if (g == 0) {
        float* ap = aux + (size_t)b * AUXC * HWSZ + y * NW + px;
#pragma unroll
        for (int oc = 0; oc < AUXC; ++oc) {
            float s = acc[oc] + red[0][oc][px] + red[1][oc][px] + red[2][oc][px];
            if (oc < 18) {
                ap[oc * HWSZ] = s + offb[oc];
            } else {
                float z = s + modb[oc - 18];
                ap[oc * HWSZ] = 2.f / (1.f + __expf(-z));
            }
        }
    }
}

// ---------------------------------------------------------------------------
// Kernel 2: deformable sampling + MFMA contraction.
// Block = 64 px x 96 oc; 4 waves; wave wv owns px n-tile [wv*16,+16).
// ESH = log2(bytes/elem) of the sampling source: 1 = bf16 planes, 2 = f32.
// Per K-step(32): batch-read 8 geo entries (b64), batch-issue 2x16 sample
// loads into static register arrays, combine -> bfr, 6x MFMA. No barriers
// in the K-loop. launch_bounds(256,4): VGPR cap 128 for deep load batches.
// MFMA 16x16x32 bf16: A[m=l&15][k=g*8+j], B[k][n=l&15],
// D col=l&15, row=g*4+r (m89-verified, validated in round 4).
// ---------------------------------------------------------------------------
template <int ESH>
__global__ __launch_bounds__(256, 4) void deform_mfma_kernel(
    const void* __restrict__ xsrc,             // (B,C,H,W) bf16 or f32
    const float* __restrict__ aux,             // (B,27,H,W)
    const unsigned short* __restrict__ wb16,   // [oc][ck] bf16
    float* __restrict__ out)                   // (B,C,H,W) pre-BN
{
    __shared__ uint2 sA[NK][66];               // packed u16 byte offsets x4
    __shared__ uint2 sW[NK][66];               // packed bf16 weights x4

    int t = threadIdx.x;
    int base = blockIdx.x * 64;
    int b = base >> 14;
    int rem0 = base & (HWSZ - 1);
    int y = rem0 >> 7;
    int x0 = rem0 & (NW - 1);                  // 0 or 64

    const float* auxb = aux + (size_t)b * AUXC * HWSZ;

    // ---- geometry: per (k, px): 4 clamped taps + mask-folded weights ----
    for (int e = t; e < 576; e += 256) {
        int px = e & 63;
        int k  = e >> 6;
        int xcol = x0 + px;
        int idx = y * NW + xcol;
        float offy = auxb[(2 * k) * HWSZ + idx];
        float offx = auxb[(2 * k + 1) * HWSZ + idx];
        float m    = auxb[(18 + k) * HWSZ + idx];
        int ky = k / 3, kx = k - 3 * (k / 3);
        float py  = (float)(y - 1 + ky) + offy;
        float pxf = (float)(xcol - 1 + kx) + offx;
        float y0f = floorf(py), x0f = floorf(pxf);
        float dy = py - y0f, dx = pxf - x0f;
        int iy0 = (int)y0f, ix0 = (int)x0f;
        int iy1 = iy0 + 1,  ix1 = ix0 + 1;

        bool vy0 = (iy0 >= 0) && (iy0 < NH);
        bool vy1 = (iy1 >= 0) && (iy1 < NH);
        bool vx0 = (ix0 >= 0) && (ix0 < NW);
        bool vx1 = (ix1 >= 0) && (ix1 < NW);
        int cy0 = min(max(iy0, 0), NH - 1);
        int cy1 = min(max(iy1, 0), NH - 1);
        int cx0 = min(max(ix0, 0), NW - 1);
        int cx1 = min(max(ix1, 0), NW - 1);

        float g00 = (1.f - dy) * (1.f - dx) * m; if (!(vy0 && vx0)) g00 = 0.f;
        float g01 = (1.f - dy) * dx * m;         if (!(vy0 && vx1)) g01 = 0.f;
        float g10 = dy * (1.f - dx) * m;         if (!(vy1 && vx0)) g10 = 0.f;
        float g11 = dy * dx * m;                 if (!(vy1 && vx1)) g11 = 0.f;

        unsigned int a0 = (unsigned int)(cy0 * NW + cx0) << ESH;  // byte offs
        unsigned int a1 = (unsigned int)(cy0 * NW + cx1) << ESH;
        unsigned int a2 = (unsigned int)(cy1 * NW + cx0) << ESH;
        unsigned int a3 = (unsigned int)(cy1 * NW + cx1) << ESH;

        uint2 ua, uw;
        ua.x = a0 | (a1 << 16);
        ua.y = a2 | (a3 << 16);
        uw.x = bf16r(g00) | (bf16r(g01) << 16);
        uw.y = bf16r(g10) | (bf16r(g11) << 16);
        sA[k][px] = ua;
        sW[k][px] = uw;
    }
    __syncthreads();

    f32x4 acc[6];
#pragma unroll
    for (int i = 0; i < 6; ++i) acc[i] = (f32x4){0.f, 0.f, 0.f, 0.f};

    const int lane15   = t & 15;
    const int g        = (t >> 4) & 3;         // k-group within wave
    const int wv       = t >> 6;               // wave id = n-tile
    const int px_local = (wv << 4) | lane15;
    const int g8       = g << 3;

    // incremental (channel, kpos) counters for kk = k0 + g8 + j
    int c_cur = g8 / 9;
    int k_cur = g8 - 9 * c_cur;

    const char* xpb = (const char*)xsrc + (((size_t)b * NC * HWSZ) << ESH);

    for (int k0 = 0; k0 < CKK; k0 += 32) {
        // A fragments: issue first (independent, L2-resident)
        bf16x8 afr[6];
#pragma unroll
        for (int i = 0; i < 6; ++i)
            afr[i] = *(const bf16x8*)(wb16 + (size_t)(i * 16 + lane15) * CKK + k0 + g8);

        // batched geometry reads (16x ds_read_b64) + counter walk
        uint2 ga[8], gw[8];
        int   cb[8];
#pragma unroll
        for (int j = 0; j < 8; ++j) {
            ga[j] = sA[k_cur][px_local];
            gw[j] = sW[k_cur][px_local];
            cb[j] = c_cur;
            bool wrap = (k_cur == 8);
            k_cur = wrap ? 0 : k_cur + 1;
            c_cur += wrap ? 1 : 0;
        }
        // advance from kk=k0+g8+8 to kk=k0+32+g8 (+24)
        c_cur += 2; k_cur += 6;
        if (k_cur >= 9) { k_cur -= 9; ++c_cur; }

        bf16x8 bfr;
#pragma unroll
        for (int h = 0; h < 2; ++h) {
            float sv[16];
#pragma unroll
            for (int jj = 0; jj < 4; ++jj) {
                int j = h * 4 + jj;
                const char* p = xpb + ((size_t)cb[j] << (14 + ESH));
                unsigned o0 = ga[j].x & 0xffffu, o1 = ga[j].x >> 16;
                unsigned o2 = ga[j].y & 0xffffu, o3 = ga[j].y >> 16;
                if (ESH == 1) {
                    sv[jj * 4 + 0] = __uint_as_float((unsigned)*(const unsigned short*)(p + o0) << 16);
                    sv[jj * 4 + 1] = __uint_as_float((unsigned)*(const unsigned short*)(p + o1) << 16);
                    sv[jj * 4 + 2] = __uint_as_float((unsigned)*(const unsigned short*)(p + o2) << 16);
                    sv[jj * 4 + 3] = __uint_as_float((unsigned)*(const unsigned short*)(p + o3) << 16);
                } else {
                    sv[jj * 4 + 0] = *(const float*)(p + o0);
                    sv[jj * 4 + 1] = *(const float*)(p + o1);
                    sv[jj * 4 + 2] = *(const float*)(p + o2);
                    sv[jj * 4 + 3] = *(const float*)(p + o3);
                }
            }
#pragma unroll
            for (int jj = 0; jj < 4; ++jj) {
                int j = h * 4 + jj;
                float w0 = __uint_as_float(gw[j].x << 16);
                float w1 = __uint_as_float(gw[j].x & 0xffff0000u);
                float w2 = __uint_as_float(gw[j].y << 16);
                float w3 = __uint_as_float(gw[j].y & 0xffff0000u);
                float s = sv[jj * 4 + 0] * w0;
                s = fmaf(sv[jj * 4 + 1], w1, s);
                s = fmaf(sv[jj * 4 + 2], w2, s);
                s = fmaf(sv[jj * 4 + 3], w3, s);
                bfr[j] = (short)bf16r(s);
            }
        }

#pragma unroll
        for (int i = 0; i < 6; ++i)
            acc[i] = __builtin_amdgcn_mfma_f32_16x16x32_bf16(afr[i], bfr, acc[i], 0, 0, 0);
    }

    float* ob = out + (size_t)b * NC * HWSZ + y * NW + x0 + px_local;
#pragma unroll
    for (int i = 0; i < 6; ++i) {
        int row0 = i * 16 + g * 4;
#pragma unroll
        for (int r = 0; r < 4; ++r)
            ob[(row0 + r) * HWSZ] = acc[i][r];
    }
}

// ---------------------------------------------------------------------------
// Kernel 3a: per-(b,c) partial sums.  Kernel 3b: finalize scale/shift.
// ---------------------------------------------------------------------------
__global__ __launch_bounds__(256) void bnstats_kernel(
    const float* __restrict__ h, float* __restrict__ part)
{
    int bc = blockIdx.x;                 // 0..383 = b*NC+c
    const float4* p = (const float4*)(h + (size_t)bc * HWSZ);
    float s = 0.f, s2 = 0.f;
    for (int i = threadIdx.x; i < HWSZ / 4; i += 256) {
        float4 v = p[i];
        s  += v.x + v.y + v.z + v.w;
        s2 += v.x * v.x + v.y * v.y + v.z * v.z + v.w * v.w;
    }
#pragma unroll
    for (int o = 32; o > 0; o >>= 1) {
        s  += __shfl_down(s, o);
        s2 += __shfl_down(s2, o);
    }
    __shared__ float red[8];
    int wv = threadIdx.x >> 6, ln = threadIdx.x & 63;
    if (ln == 0) { red[wv] = s; red[4 + wv] = s2; }
    __syncthreads();
    if (threadIdx.x == 0) {
        part[bc]            = red[0] + red[1] + red[2] + red[3];
        part[NB * NC + bc]  = red[4] + red[5] + red[6] + red[7];
    }
}

__global__ __launch_bounds__(128) void bnfinalize_kernel(
    const float* __restrict__ part, const float* __restrict__ g,
    const float* __restrict__ bt, float* __restrict__ sc)
{
    int c = threadIdx.x;
    if (c >= NC) return;
    float s = 0.f, s2 = 0.f;
#pragma unroll
    for (int b = 0; b < NB; ++b) {
        s  += part[b * NC + c];
        s2 += part[NB * NC + b * NC + c];
    }
    const float inv_n = 1.f / (float)(NB * HWSZ);
    float mean = s * inv_n;
    float var  = s2 * inv_n - mean * mean;
    float scale = g[c] * rsqrtf(var + 1e-5f);
    sc[c] = scale;
    sc[NC + c] = bt[c] - mean * scale;
}

// ---------------------------------------------------------------------------
// Kernel 4: BN + leaky ReLU in place; optionally emit bf16 copy for sampling.
// ---------------------------------------------------------------------------
template <bool E16>
__global__ __launch_bounds__(256) void bnlrelu_kernel(
    float* __restrict__ h, const float* __restrict__ sc,
    unsigned short* __restrict__ h16)
{
    const int n4 = NB * NC * HWSZ / 4;
    for (int i = blockIdx.x * 256 + threadIdx.x; i < n4; i += gridDim.x * 256) {
        int c = (i >> 12) % NC;
        float scale = sc[c], shift = sc[NC + c];
        float4 v = ((const float4*)h)[i];
        float4 o;
        o.x = fmaf(scale, v.x, shift); o.x = o.x >= 0.f ? o.x : 0.1f * o.x;
        o.y = fmaf(scale, v.y, shift); o.y = o.y >= 0.f ? o.y : 0.1f * o.y;
        o.z = fmaf(scale, v.z, shift); o.z = o.z >= 0.f ? o.z : 0.1f * o.z;
        o.w = fmaf(scale, v.w, shift); o.w = o.w >= 0.f ? o.w : 0.1f * o.w;
        ((float4*)h)[i] = o;
        if (E16) {
            ushort4 u;
            u.x = (unsigned short)bf16r(o.x);
            u.y = (unsigned short)bf16r(o.y);
            u.z = (unsigned short)bf16r(o.z);
            u.w = (unsigned short)bf16r(o.w);
            ((ushort4*)h16)[i] = u;
        }
    }
}

// ---------------------------------------------------------------------------
// Kernel 5: out = x + BN(out_raw) in place
// ---------------------------------------------------------------------------
__global__ __launch_bounds__(256) void final_kernel(
    float* __restrict__ out, const float* __restrict__ x,
    const float* __restrict__ sc)
{
    const int n4 = NB * NC * HWSZ / 4;
    for (int i = blockIdx.x * 256 + threadIdx.x; i < n4; i += gridDim.x * 256) {
        int c = (i >> 12) % NC;
        float scale = sc[c], shift = sc[NC + c];
        float4 v = ((const float4*)out)[i];
        float4 xv = ((const float4*)x)[i];
        float4 o;
        o.x = xv.x + fmaf(scale, v.x, shift);
        o.y = xv.y + fmaf(scale, v.y, shift);
        o.z = xv.z + fmaf(scale, v.z, shift);
        o.w = xv.w + fmaf(scale, v.w, shift);
        ((float4*)out)[i] = o;
    }
}

// ---------------------------------------------------------------------------
extern "C" void kernel_launch(void* const* d_in, const int* in_sizes, int n_in,
                              void* d_out, int out_size, void* d_ws, size_t ws_size,
                              hipStream_t stream)
{
    const float* x        = (const float*)d_in[0];
    const float* d1_off_w = (const float*)d_in[1];
    const float* d1_off_b = (const float*)d_in[2];
    const float* d1_mod_w = (const float*)d_in[3];
    const float* d1_mod_b = (const float*)d_in[4];
    const float* d1_w     = (const float*)d_in[5];
    const float* d2_off_w = (const float*)d_in[6];
    const float* d2_off_b = (const float*)d_in[7];
    const float* d2_mod_w = (const float*)d_in[8];
    const float* d2_mod_b = (const float*)d_in[9];
    const float* d2_w     = (const float*)d_in[10];
    const float* bn_g     = (const float*)d_in[11];
    const float* bn_b     = (const float*)d_in[12];
    float* out = (float*)d_out;

    // ws layout (floats): h1 | aux | wT | wb16 | sc | part | [xb16]
    const size_t nImg = (size_t)NB * NC * HWSZ;       // 6291456
    float* h1   = (float*)d_ws;
    float* aux  = h1   + nImg;
    float* wT   = aux  + (size_t)NB * AUXC * HWSZ;
    unsigned short* wb16 = (unsigned short*)(wT + WT_ELEMS);
    float* sc   = wT + WT_ELEMS + WB_ELEMS / 2;
    float* part = sc + 2 * NC;
    unsigned short* xb16 = (unsigned short*)(part + 2 * NB * NC);

    const size_t base_floats = nImg + (size_t)NB * AUXC * HWSZ + WT_ELEMS
                             + WB_ELEMS / 2 + 2 * NC + 2 * NB * NC;
    const bool useB16 = ws_size >= (base_floats + nImg / 2) * sizeof(float);

    const int npix = NB * HWSZ;                       // 65536
    const int prep_blocks = (WT_ELEMS + WB_ELEMS + 255) / 256;

    // ---- layer 1 ----
    prep_weights_kernel<<<prep_blocks, 256, 0, stream>>>(d1_off_w, d1_mod_w, d1_w, wT, wb16);
    conv27_kernel<<<NB * NH, 512, 0, stream>>>(x, wT, d1_off_b, d1_mod_b, aux);
    if (useB16) {
        tobf16_kernel<<<2048, 256, 0, stream>>>(x, xb16);
        deform_mfma_kernel<1><<<npix / 64, 256, 0, stream>>>(xb16, aux, wb16, h1);
    } else {
        deform_mfma_kernel<2><<<npix / 64, 256, 0, stream>>>(x, aux, wb16, h1);
    }
    bnstats_kernel<<<NB * NC, 256, 0, stream>>>(h1, part);
    bnfinalize_kernel<<<1, 128, 0, stream>>>(part, bn_g, bn_b, sc);
    if (useB16)
        bnlrelu_kernel<true><<<2048, 256, 0, stream>>>(h1, sc, xb16);
    else
        bnlrelu_kernel<false><<<2048, 256, 0, stream>>>(h1, sc, nullptr);

    // ---- layer 2 ----
    prep_weights_kernel<<<prep_blocks, 256, 0, stream>>>(d2_off_w, d2_mod_w, d2_w, wT, wb16);
    conv27_kernel<<<NB * NH, 512, 0, stream>>>(h1, wT, d2_off_b, d2_mod_b, aux);
    if (useB16)
        deform_mfma_kernel<1><<<npix / 64, 256, 0, stream>>>(xb16, aux, wb16, out);
    else
        deform_mfma_kernel<2><<<npix / 64, 256, 0, stream>>>(h1, aux, wb16, out);
    bnstats_kernel<<<NB * NC, 256, 0, stream>>>(out, part);
    bnfinalize_kernel<<<1, 128, 0, stream>>>(part, bn_g, bn_b, sc);
    final_kernel<<<2048, 256, 0, stream>>>(out, x, sc);
}

// Round 6
// 804.880 us; speedup vs baseline: 1.0139x; 1.0139x over previous
//
#include <hip/hip_runtime.h>
#include <math.h>

#define NB 4
#define NC 96
#define NH 128
#define NW 128
#define HWSZ (NH * NW)          // 16384
#define NK 9
#define AUXC 27                 // 18 offset + 9 mask channels
#define CKK (NC * NK)           // 864
#define WT_STRIDE 28            // 27 outputs + 1 pad
#define WT_ELEMS (CKK * WT_STRIDE)      // 24192
#define WB_ELEMS (NC * CKK)             // 82944 bf16 deform weights

typedef __attribute__((ext_vector_type(8))) short bf16x8;
typedef __attribute__((ext_vector_type(4))) float f32x4;

__device__ __forceinline__ unsigned int bf16r(float f) {
    unsigned int u = __float_as_uint(f);
    u += 0x7fffu + ((u >> 16) & 1u);
    return u >> 16;                      // RNE bf16 bits
}

// ---------------------------------------------------------------------------
// Kernel 0: weight prep.
// ---------------------------------------------------------------------------
__global__ __launch_bounds__(256) void prep_weights_kernel(
    const float* __restrict__ offw, const float* __restrict__ modw,
    const float* __restrict__ w,
    float* __restrict__ wT, unsigned short* __restrict__ wb16)
{
    int idx = blockIdx.x * 256 + threadIdx.x;
    if (idx < WT_ELEMS) {
        int row = idx / WT_STRIDE;          // c*9+tap
        int col = idx - row * WT_STRIDE;    // oc
        float v = 0.f;
        if (col < 18)      v = offw[col * CKK + row];
        else if (col < 27) v = modw[(col - 18) * CKK + row];
        wT[idx] = v;
    }
    int j = idx - WT_ELEMS;
    if (j >= 0 && j < WB_ELEMS) {
        wb16[j] = (unsigned short)bf16r(w[j]);
    }
}

// ---------------------------------------------------------------------------
// Kernel 0b: f32 -> bf16 plane conversion (deform sampling source)
// ---------------------------------------------------------------------------
__global__ __launch_bounds__(256) void tobf16_kernel(
    const float* __restrict__ in, unsigned short* __restrict__ o)
{
    const int n4 = NB * NC * HWSZ / 4;
    for (int i = blockIdx.x * 256 + threadIdx.x; i < n4; i += gridDim.x * 256) {
        float4 v = ((const float4*)in)[i];
        ushort4 u;
        u.x = (unsigned short)bf16r(v.x);
        u.y = (unsigned short)bf16r(v.y);
        u.z = (unsigned short)bf16r(v.z);
        u.w = (unsigned short)bf16r(v.w);
        ((ushort4*)o)[i] = u;
    }
}

// ---------------------------------------------------------------------------
// Kernel 1: 3x3 conv -> 18 offset + 9 mask (2*sigmoid). fp32.
// XCD-contiguous swizzle: XCD k owns a 64-row slab of one image (L2 local).
// ---------------------------------------------------------------------------
__global__ __launch_bounds__(512) void conv27_kernel(
    const float* __restrict__ in,
    const float* __restrict__ wT,
    const float* __restrict__ offb, const float* __restrict__ modb,
    float* __restrict__ aux)
{
    __shared__ float red[3][AUXC][NW];      // 41472 B

    int t  = threadIdx.x;
    int px = t & 127;
    int g  = t >> 7;
    int bid = blockIdx.x;
    int work = ((bid & 7) << 6) | (bid >> 3);   // bijective, 512 wg
    int b  = work >> 7;
    int y  = work & 127;

    const bool hasT = (y > 0), hasB = (y < NH - 1);   // uniform
    const int offT = hasT ? NW : 0;
    const int offB = hasB ? NW : 0;
    int pxl = px > 0 ? px - 1 : 0;
    int pxr = px < NW - 1 ? px + 1 : NW - 1;
    const float mL = (px == 0) ? 0.f : 1.f;
    const float mR = (px == NW - 1) ? 0.f : 1.f;

    float acc[AUXC];
#pragma unroll
    for (int i = 0; i < AUXC; ++i) acc[i] = 0.f;

    const float* imgb = in + (size_t)b * NC * HWSZ + y * NW;
    int c0 = g * 24;

    for (int c = c0; c < c0 + 24; ++c) {
        const float* rm = imgb + c * HWSZ;
        const float* rt = rm - offT;
        const float* rb = rm + offB;
        float t0 = rt[pxl], t1 = rt[px], t2 = rt[pxr];
        float t3 = rm[pxl], t4 = rm[px], t5 = rm[pxr];
        float t6 = rb[pxl], t7 = rb[px], t8 = rb[pxr];
        if (!hasT) { t0 = 0.f; t1 = 0.f; t2 = 0.f; }
        if (!hasB) { t6 = 0.f; t7 = 0.f; t8 = 0.f; }
        t0 *= mL; t3 *= mL; t6 *= mL;
        t2 *= mR; t5 *= mR; t8 *= mR;

        const float* wb = wT + c * NK * WT_STRIDE;     // uniform -> s_loads
#pragma unroll
        for (int oc = 0; oc < AUXC; ++oc) {
            float a = acc[oc];
            a = fmaf(t0, wb[0 * WT_STRIDE + oc], a);
            a = fmaf(t1, wb[1 * WT_STRIDE + oc], a);
            a = fmaf(t2, wb[2 * WT_STRIDE + oc], a);
            a = fmaf(t3, wb[3 * WT_STRIDE + oc], a);
            a = fmaf(t4, wb[4 * WT_STRIDE + oc], a);
            a = fmaf(t5, wb[5 * WT_STRIDE + oc], a);
            a = fmaf(t6, wb[6 * WT_STRIDE + oc], a);
            a = fmaf(t7, wb[7 * WT_STRIDE + oc], a);
            a = fmaf(t8, wb[8 * WT_STRIDE + oc], a);
            acc[oc] = a;
        }
    }

    if (g > 0) {
#pragma unroll
        for (int oc = 0; oc < AUXC; ++oc) red[g - 1][oc][px] = acc[oc];
    }
    __syncthreads();
    if (g == 0) {
        float* ap = aux + (size_t)b * AUXC * HWSZ + y * NW + px;
#pragma unroll
        for (int oc = 0; oc < AUXC; ++oc) {
            float s = acc[oc] + red[0][oc][px] + red[1][oc][px] + red[2][oc][px];
            if (oc < 18) {
                ap[oc * HWSZ] = s + offb[oc];
            } else {
                float z = s + modb[oc - 18];
                ap[oc * HWSZ] = 2.f / (1.f + __expf(-z));
            }
        }
    }
}

// ---------------------------------------------------------------------------
// Kernel 2: deformable sampling + MFMA contraction, K-split x2.
// Block = 512 threads = 8 waves: wave wv -> n-tile (wv&3), K-half (wv>>2).
// Each n-tile wave pair: 16 px, 6 oc m-tiles, 14/13 K-steps of 32.
// Upper K-half reduces into lower via LDS ([tile][elem][lane], conflict-free).
// XCD-contiguous swizzle: XCD k owns a 64-row slab of one image.
// ESH: 1 = bf16 sampling planes, 2 = f32.
// ---------------------------------------------------------------------------
template <int ESH>
__global__ __launch_bounds__(512, 4) void deform_mfma_kernel(
    const void* __restrict__ xsrc,             // (B,C,H,W) bf16 or f32
    const float* __restrict__ aux,             // (B,27,H,W)
    const unsigned short* __restrict__ wb16,   // [oc][ck] bf16
    float* __restrict__ out)                   // (B,C,H,W) pre-BN
{
    __shared__ uint2 sA[NK][66];               // packed u16 byte offsets x4
    __shared__ uint2 sW[NK][66];               // packed bf16 weights x4
    __shared__ float sRed[4][24][64];          // K-split reduction

    int t = threadIdx.x;
    int bid = blockIdx.x;
    int work = ((bid & 7) << 7) | (bid >> 3);  // bijective, 1024 wg
    int base = work * 64;
    int b = base >> 14;
    int rem0 = base & (HWSZ - 1);
    int y = rem0 >> 7;
    int x0 = rem0 & (NW - 1);                  // 0 or 64

    const float* auxb = aux + (size_t)b * AUXC * HWSZ;

    // ---- geometry: per (k, px): 4 clamped taps + mask-folded weights ----
    for (int e = t; e < 576; e += 512) {
        int px = e & 63;
        int k  = e >> 6;
        int xcol = x0 + px;
        int idx = y * NW + xcol;
        float offy = auxb[(2 * k) * HWSZ + idx];
        float offx = auxb[(2 * k + 1) * HWSZ + idx];
        float m    = auxb[(18 + k) * HWSZ + idx];
        int ky = k / 3, kx = k - 3 * (k / 3);
        float py  = (float)(y - 1 + ky) + offy;
        float pxf = (float)(xcol - 1 + kx) + offx;
        float y0f = floorf(py), x0f = floorf(pxf);
        float dy = py - y0f, dx = pxf - x0f;
        int iy0 = (int)y0f, ix0 = (int)x0f;
        int iy1 = iy0 + 1,  ix1 = ix0 + 1;

        bool vy0 = (iy0 >= 0) && (iy0 < NH);
        bool vy1 = (iy1 >= 0) && (iy1 < NH);
        bool vx0 = (ix0 >= 0) && (ix0 < NW);
        bool vx1 = (ix1 >= 0) && (ix1 < NW);
        int cy0 = min(max(iy0, 0), NH - 1);
        int cy1 = min(max(iy1, 0), NH - 1);
        int cx0 = min(max(ix0, 0), NW - 1);
        int cx1 = min(max(ix1, 0), NW - 1);

        float g00 = (1.f - dy) * (1.f - dx) * m; if (!(vy0 && vx0)) g00 = 0.f;
        float g01 = (1.f - dy) * dx * m;         if (!(vy0 && vx1)) g01 = 0.f;
        float g10 = dy * (1.f - dx) * m;         if (!(vy1 && vx0)) g10 = 0.f;
        float g11 = dy * dx * m;                 if (!(vy1 && vx1)) g11 = 0.f;

        unsigned int a0 = (unsigned int)(cy0 * NW + cx0) << ESH;  // byte offs
        unsigned int a1 = (unsigned int)(cy0 * NW + cx1) << ESH;
        unsigned int a2 = (unsigned int)(cy1 * NW + cx0) << ESH;
        unsigned int a3 = (unsigned int)(cy1 * NW + cx1) << ESH;

        uint2 ua, uw;
        ua.x = a0 | (a1 << 16);
        ua.y = a2 | (a3 << 16);
        uw.x = bf16r(g00) | (bf16r(g01) << 16);
        uw.y = bf16r(g10) | (bf16r(g11) << 16);
        sA[k][px] = ua;
        sW[k][px] = uw;
    }
    __syncthreads();

    f32x4 acc[6];
#pragma unroll
    for (int i = 0; i < 6; ++i) acc[i] = (f32x4){0.f, 0.f, 0.f, 0.f};

    const int lane15   = t & 15;
    const int g        = (t >> 4) & 3;         // k-group within wave
    const int wv       = t >> 6;               // wave id
    const int nt       = wv & 3;               // n-tile
    const int ks       = wv >> 2;              // K-split half
    const int px_local = (nt << 4) | lane15;
    const int g8       = g << 3;
    const int l64      = t & 63;

    const int k0beg = ks ? 448 : 0;            // 14 / 13 K-steps
    const int k0end = ks ? CKK : 448;

    // incremental (channel, kpos) counters for kk = k0 + g8 + j
    int c_cur = (k0beg + g8) / 9;
    int k_cur = (k0beg + g8) - 9 * c_cur;

    const char* xpb = (const char*)xsrc + (((size_t)b * NC * HWSZ) << ESH);

    for (int k0 = k0beg; k0 < k0end; k0 += 32) {
        // A fragments (L2-resident weights)
        bf16x8 afr[6];
#pragma unroll
        for (int i = 0; i < 6; ++i)
            afr[i] = *(const bf16x8*)(wb16 + (size_t)(i * 16 + lane15) * CKK + k0 + g8);

        // batched geometry reads + counter walk
        uint2 ga[8], gw[8];
        int   cb[8];
#pragma unroll
        for (int j = 0; j < 8; ++j) {
            ga[j] = sA[k_cur][px_local];
            gw[j] = sW[k_cur][px_local];
            cb[j] = c_cur;
            bool wrap = (k_cur == 8);
            k_cur = wrap ? 0 : k_cur + 1;
            c_cur += wrap ? 1 : 0;
        }
        c_cur += 2; k_cur += 6;                 // advance +24 to next k0
        if (k_cur >= 9) { k_cur -= 9; ++c_cur; }

        bf16x8 bfr;
#pragma unroll
        for (int h = 0; h < 2; ++h) {
            float sv[16];
#pragma unroll
            for (int jj = 0; jj < 4; ++jj) {
                int j = h * 4 + jj;
                const char* p = xpb + ((size_t)cb[j] << (14 + ESH));
                unsigned o0 = ga[j].x & 0xffffu, o1 = ga[j].x >> 16;
                unsigned o2 = ga[j].y & 0xffffu, o3 = ga[j].y >> 16;
                if (ESH == 1) {
                    sv[jj * 4 + 0] = __uint_as_float((unsigned)*(const unsigned short*)(p + o0) << 16);
                    sv[jj * 4 + 1] = __uint_as_float((unsigned)*(const unsigned short*)(p + o1) << 16);
                    sv[jj * 4 + 2] = __uint_as_float((unsigned)*(const unsigned short*)(p + o2) << 16);
                    sv[jj * 4 + 3] = __uint_as_float((unsigned)*(const unsigned short*)(p + o3) << 16);
                } else {
                    sv[jj * 4 + 0] = *(const float*)(p + o0);
                    sv[jj * 4 + 1] = *(const float*)(p + o1);
                    sv[jj * 4 + 2] = *(const float*)(p + o2);
                    sv[jj * 4 + 3] = *(const float*)(p + o3);
                }
            }
#pragma unroll
            for (int jj = 0; jj < 4; ++jj) {
                int j = h * 4 + jj;
                float w0 = __uint_as_float(gw[j].x << 16);
                float w1 = __uint_as_float(gw[j].x & 0xffff0000u);
                float w2 = __uint_as_float(gw[j].y << 16);
                float w3 = __uint_as_float(gw[j].y & 0xffff0000u);
                float s = sv[jj * 4 + 0] * w0;
                s = fmaf(sv[jj * 4 + 1], w1, s);
                s = fmaf(sv[jj * 4 + 2], w2, s);
                s = fmaf(sv[jj * 4 + 3], w3, s);
                bfr[j] = (short)bf16r(s);
            }
        }

#pragma unroll
        for (int i = 0; i < 6; ++i)
            acc[i] = __builtin_amdgcn_mfma_f32_16x16x32_bf16(afr[i], bfr, acc[i], 0, 0, 0);
    }

    // ---- K-split reduce: upper half -> LDS, lower half adds & stores ----
    if (ks == 1) {
#pragma unroll
        for (int i = 0; i < 6; ++i)
#pragma unroll
            for (int r = 0; r < 4; ++r)
                sRed[nt][i * 4 + r][l64] = acc[i][r];
    }
    __syncthreads();
    if (ks == 0) {
        float* ob = out + (size_t)b * NC * HWSZ + y * NW + x0 + px_local;
#pragma unroll
        for (int i = 0; i < 6; ++i) {
            int row0 = i * 16 + g * 4;
#pragma unroll
            for (int r = 0; r < 4; ++r)
                ob[(row0 + r) * HWSZ] = acc[i][r] + sRed[nt][i * 4 + r][l64];
        }
    }
}

// ---------------------------------------------------------------------------
// Kernel 3a: per-(b,c) partial sums.  Kernel 3b: finalize scale/shift.
// ---------------------------------------------------------------------------
__global__ __launch_bounds__(256) void bnstats_kernel(
    const float* __restrict__ h, float* __restrict__ part)
{
    int bc = blockIdx.x;                 // 0..383 = b*NC+c
    const float4* p = (const float4*)(h + (size_t)bc * HWSZ);
    float s = 0.f, s2 = 0.f;
    for (int i = threadIdx.x; i < HWSZ / 4; i += 256) {
        float4 v = p[i];
        s  += v.x + v.y + v.z + v.w;
        s2 += v.x * v.x + v.y * v.y + v.z * v.z + v.w * v.w;
    }
#pragma unroll
    for (int o = 32; o > 0; o >>= 1) {
        s  += __shfl_down(s, o);
        s2 += __shfl_down(s2, o);
    }
    __shared__ float red[8];
    int wv = threadIdx.x >> 6, ln = threadIdx.x & 63;
    if (ln == 0) { red[wv] = s; red[4 + wv] = s2; }
    __syncthreads();
    if (threadIdx.x == 0) {
        part[bc]            = red[0] + red[1] + red[2] + red[3];
        part[NB * NC + bc]  = red[4] + red[5] + red[6] + red[7];
    }
}

__global__ __launch_bounds__(128) void bnfinalize_kernel(
    const float* __restrict__ part, const float* __restrict__ g,
    const float* __restrict__ bt, float* __restrict__ sc)
{
    int c = threadIdx.x;
    if (c >= NC) return;
    float s = 0.f, s2 = 0.f;
#pragma unroll
    for (int b = 0; b < NB; ++b) {
        s  += part[b * NC + c];
        s2 += part[NB * NC + b * NC + c];
    }
    const float inv_n = 1.f / (float)(NB * HWSZ);
    float mean = s * inv_n;
    float var  = s2 * inv_n - mean * mean;
    float scale = g[c] * rsqrtf(var + 1e-5f);
    sc[c] = scale;
    sc[NC + c] = bt[c] - mean * scale;
}

// ---------------------------------------------------------------------------
// Kernel 4: BN + leaky ReLU in place; optionally emit bf16 copy for sampling.
// ---------------------------------------------------------------------------
template <bool E16>
__global__ __launch_bounds__(256) void bnlrelu_kernel(
    float* __restrict__ h, const float* __restrict__ sc,
    unsigned short* __restrict__ h16)
{
    const int n4 = NB * NC * HWSZ / 4;
    for (int i = blockIdx.x * 256 + threadIdx.x; i < n4; i += gridDim.x * 256) {
        int c = (i >> 12) % NC;
        float scale = sc[c], shift = sc[NC + c];
        float4 v = ((const float4*)h)[i];
        float4 o;
        o.x = fmaf(scale, v.x, shift); o.x = o.x >= 0.f ? o.x : 0.1f * o.x;
        o.y = fmaf(scale, v.y, shift); o.y = o.y >= 0.f ? o.y : 0.1f * o.y;
        o.z = fmaf(scale, v.z, shift); o.z = o.z >= 0.f ? o.z : 0.1f * o.z;
        o.w = fmaf(scale, v.w, shift); o.w = o.w >= 0.f ? o.w : 0.1f * o.w;
        ((float4*)h)[i] = o;
        if (E16) {
            ushort4 u;
            u.x = (unsigned short)bf16r(o.x);
            u.y = (unsigned short)bf16r(o.y);
            u.z = (unsigned short)bf16r(o.z);
            u.w = (unsigned short)bf16r(o.w);
            ((ushort4*)h16)[i] = u;
        }
    }
}

// ---------------------------------------------------------------------------
// Kernel 5: out = x + BN(out_raw) in place
// ---------------------------------------------------------------------------
__global__ __launch_bounds__(256) void final_kernel(
    float* __restrict__ out, const float* __restrict__ x,
    const float* __restrict__ sc)
{
    const int n4 = NB * NC * HWSZ / 4;
    for (int i = blockIdx.x * 256 + threadIdx.x; i < n4; i += gridDim.x * 256) {
        int c = (i >> 12) % NC;
        float scale = sc[c], shift = sc[NC + c];
        float4 v = ((const float4*)out)[i];
        float4 xv = ((const float4*)x)[i];
        float4 o;
        o.x = xv.x + fmaf(scale, v.x, shift);
        o.y = xv.y + fmaf(scale, v.y, shift);
        o.z = xv.z + fmaf(scale, v.z, shift);
        o.w = xv.w + fmaf(scale, v.w, shift);
        ((float4*)out)[i] = o;
    }
}

// ---------------------------------------------------------------------------
extern "C" void kernel_launch(void* const* d_in, const int* in_sizes, int n_in,
                              void* d_out, int out_size, void* d_ws, size_t ws_size,
                              hipStream_t stream)
{
    const float* x        = (const float*)d_in[0];
    const float* d1_off_w = (const float*)d_in[1];
    const float* d1_off_b = (const float*)d_in[2];
    const float* d1_mod_w = (const float*)d_in[3];
    const float* d1_mod_b = (const float*)d_in[4];
    const float* d1_w     = (const float*)d_in[5];
    const float* d2_off_w = (const float*)d_in[6];
    const float* d2_off_b = (const float*)d_in[7];
    const float* d2_mod_w = (const float*)d_in[8];
    const float* d2_mod_b = (const float*)d_in[9];
    const float* d2_w     = (const float*)d_in[10];
    const float* bn_g     = (const float*)d_in[11];
    const float* bn_b     = (const float*)d_in[12];
    float* out = (float*)d_out;

    // ws layout (floats): h1 | aux | wT | wb16 | sc | part | [xb16]
    const size_t nImg = (size_t)NB * NC * HWSZ;       // 6291456
    float* h1   = (float*)d_ws;
    float* aux  = h1   + nImg;
    float* wT   = aux  + (size_t)NB * AUXC * HWSZ;
    unsigned short* wb16 = (unsigned short*)(wT + WT_ELEMS);
    float* sc   = wT + WT_ELEMS + WB_ELEMS / 2;
    float* part = sc + 2 * NC;
    unsigned short* xb16 = (unsigned short*)(part + 2 * NB * NC);

    const size_t base_floats = nImg + (size_t)NB * AUXC * HWSZ + WT_ELEMS
                             + WB_ELEMS / 2 + 2 * NC + 2 * NB * NC;
    const bool useB16 = ws_size >= (base_floats + nImg / 2) * sizeof(float);

    const int npix = NB * HWSZ;                       // 65536
    const int prep_blocks = (WT_ELEMS + WB_ELEMS + 255) / 256;

    // ---- layer 1 ----
    prep_weights_kernel<<<prep_blocks, 256, 0, stream>>>(d1_off_w, d1_mod_w, d1_w, wT, wb16);
    conv27_kernel<<<NB * NH, 512, 0, stream>>>(x, wT, d1_off_b, d1_mod_b, aux);
    if (useB16) {
        tobf16_kernel<<<2048, 256, 0, stream>>>(x, xb16);
        deform_mfma_kernel<1><<<npix / 64, 512, 0, stream>>>(xb16, aux, wb16, h1);
    } else {
        deform_mfma_kernel<2><<<npix / 64, 512, 0, stream>>>(x, aux, wb16, h1);
    }
    bnstats_kernel<<<NB * NC, 256, 0, stream>>>(h1, part);
    bnfinalize_kernel<<<1, 128, 0, stream>>>(part, bn_g, bn_b, sc);
    if (useB16)
        bnlrelu_kernel<true><<<2048, 256, 0, stream>>>(h1, sc, xb16);
    else
        bnlrelu_kernel<false><<<2048, 256, 0, stream>>>(h1, sc, nullptr);

    // ---- layer 2 ----
    prep_weights_kernel<<<prep_blocks, 256, 0, stream>>>(d2_off_w, d2_mod_w, d2_w, wT, wb16);
    conv27_kernel<<<NB * NH, 512, 0, stream>>>(h1, wT, d2_off_b, d2_mod_b, aux);
    if (useB16)
        deform_mfma_kernel<1><<<npix / 64, 512, 0, stream>>>(xb16, aux, wb16, out);
    else
        deform_mfma_kernel<2><<<npix / 64, 512, 0, stream>>>(h1, aux, wb16, out);
    bnstats_kernel<<<NB * NC, 256, 0, stream>>>(out, part);
    bnfinalize_kernel<<<1, 128, 0, stream>>>(part, bn_g, bn_b, sc);
    final_kernel<<<2048, 256, 0, stream>>>(out, x, sc);
}

// Round 7
// 562.842 us; speedup vs baseline: 1.4500x; 1.4300x over previous
//
#include <hip/hip_runtime.h>
#include <math.h>

#define NB 4
#define NC 96
#define NH 128
#define NW 128
#define HWSZ (NH * NW)          // 16384
#define NK 9
#define AUXC 27                 // 18 offset + 9 mask channels
#define CKK (NC * NK)           // 864
#define WT_STRIDE 28            // 27 outputs + 1 pad
#define WT_ELEMS (CKK * WT_STRIDE)      // 24192
#define WB_ELEMS (NC * CKK)             // 82944 bf16 deform weights
#define PIXB (NC * 2)           // 192 bytes per NHWC pixel record

typedef __attribute__((ext_vector_type(8))) short bf16x8;
typedef __attribute__((ext_vector_type(4))) float f32x4;

__device__ __forceinline__ unsigned int bf16r(float f) {
    unsigned int u = __float_as_uint(f);
    u += 0x7fffu + ((u >> 16) & 1u);
    return u >> 16;                      // RNE bf16 bits
}
__device__ __forceinline__ float uaf(unsigned int u) { return __uint_as_float(u); }

// ---------------------------------------------------------------------------
// Kernel 0: weight prep.
//   wT[(c*9+tap)*28 + oc]        fp32 (conv27)
//   wb16[oc*864 + ktap*96 + c]   bf16 (deform MFMA A, tap-major K order)
// ---------------------------------------------------------------------------
__global__ __launch_bounds__(256) void prep_weights_kernel(
    const float* __restrict__ offw, const float* __restrict__ modw,
    const float* __restrict__ w,
    float* __restrict__ wT, unsigned short* __restrict__ wb16)
{
    int idx = blockIdx.x * 256 + threadIdx.x;
    if (idx < WT_ELEMS) {
        int row = idx / WT_STRIDE;          // c*9+tap
        int col = idx - row * WT_STRIDE;    // oc
        float v = 0.f;
        if (col < 18)      v = offw[col * CKK + row];
        else if (col < 27) v = modw[(col - 18) * CKK + row];
        wT[idx] = v;
    }
    int j = idx - WT_ELEMS;
    if (j >= 0 && j < WB_ELEMS) {
        int oc   = j / CKK;
        int rem  = j - oc * CKK;            // ktap*96 + c
        int ktap = rem / NC;
        int c    = rem - ktap * NC;
        wb16[j] = (unsigned short)bf16r(w[oc * CKK + c * NK + ktap]);
    }
}

// ---------------------------------------------------------------------------
// Kernel 0b: NCHW f32 -> NHWC bf16 transpose (LDS-tiled, coalesced both ways)
// Block: 256 thr, tile = 64 px x 96 ch. Grid = NB*HWSZ/64 = 1024.
// ---------------------------------------------------------------------------
__global__ __launch_bounds__(256) void nhwc_kernel(
    const float* __restrict__ in, unsigned short* __restrict__ o)
{
    __shared__ unsigned short tile[64][98];     // pad 96->98 (bank spread)
    int t = threadIdx.x;
    int blk = blockIdx.x;
    int b  = blk >> 8;
    int p0 = (blk & 255) * 64;
    const float* ib = in + (size_t)b * NC * HWSZ + p0;

    // read: e = c*64 + px, float2 along px
#pragma unroll
    for (int r = 0; r < 12; ++r) {
        int e = (r * 256 + t) * 2;
        int c = e >> 6, px = e & 63;
        float2 v = *(const float2*)(ib + c * HWSZ + px);
        tile[px][c]     = (unsigned short)bf16r(v.x);
        tile[px + 1][c] = (unsigned short)bf16r(v.y);
    }
    __syncthreads();

    // write: e = px*96 + c, ushort2 along c (96 even, pairs never cross px)
    unsigned short* ob = o + ((size_t)b * HWSZ + p0) * NC;
#pragma unroll
    for (int r = 0; r < 12; ++r) {
        int e = (r * 256 + t) * 2;
        int px = e / 96, c = e - px * 96;
        ushort2 u;
        u.x = tile[px][c];
        u.y = tile[px][c + 1];
        *(ushort2*)(ob + e) = u;
    }
}

// ---------------------------------------------------------------------------
// Kernel 1: 3x3 conv -> 18 offset + 9 mask (2*sigmoid). fp32, XCD swizzle.
// ---------------------------------------------------------------------------
__global__ __launch_bounds__(512) void conv27_kernel(
    const float* __restrict__ in,
    const float* __restrict__ wT,
    const float* __restrict__ offb, const float* __restrict__ modb,
    float* __restrict__ aux)
{
    __shared__ float red[3][AUXC][NW];      // 41472 B

    int t  = threadIdx.x;
    int px = t & 127;
    int g  = t >> 7;
    int bid = blockIdx.x;
    int work = ((bid & 7) << 6) | (bid >> 3);   // bijective, 512 wg
    int b  = work >> 7;
    int y  = work & 127;

    const bool hasT = (y > 0), hasB = (y < NH - 1);   // uniform
    const int offT = hasT ? NW : 0;
    const int offB = hasB ? NW : 0;
    int pxl = px > 0 ? px - 1 : 0;
    int pxr = px < NW - 1 ? px + 1 : NW - 1;
    const float mL = (px == 0) ? 0.f : 1.f;
    const float mR = (px == NW - 1) ? 0.f : 1.f;

    float acc[AUXC];
#pragma unroll
    for (int i = 0; i < AUXC; ++i) acc[i] = 0.f;

    const float* imgb = in + (size_t)b * NC * HWSZ + y * NW;
    int c0 = g * 24;

    for (int c = c0; c < c0 + 24; ++c) {
        const float* rm = imgb + c * HWSZ;
        const float* rt = rm - offT;
        const float* rb = rm + offB;
        float t0 = rt[pxl], t1 = rt[px], t2 = rt[pxr];
        float t3 = rm[pxl], t4 = rm[px], t5 = rm[pxr];
        float t6 = rb[pxl], t7 = rb[px], t8 = rb[pxr];
        if (!hasT) { t0 = 0.f; t1 = 0.f; t2 = 0.f; }
        if (!hasB) { t6 = 0.f; t7 = 0.f; t8 = 0.f; }
        t0 *= mL; t3 *= mL; t6 *= mL;
        t2 *= mR; t5 *= mR; t8 *= mR;

        const float* wb = wT + c * NK * WT_STRIDE;     // uniform -> s_loads
#pragma unroll
        for (int oc = 0; oc < AUXC; ++oc) {
            float a = acc[oc];
            a = fmaf(t0, wb[0 * WT_STRIDE + oc], a);
            a = fmaf(t1, wb[1 * WT_STRIDE + oc], a);
            a = fmaf(t2, wb[2 * WT_STRIDE + oc], a);
            a = fmaf(t3, wb[3 * WT_STRIDE + oc], a);
            a = fmaf(t4, wb[4 * WT_STRIDE + oc], a);
            a = fmaf(t5, wb[5 * WT_STRIDE + oc], a);
            a = fmaf(t6, wb[6 * WT_STRIDE + oc], a);
            a = fmaf(t7, wb[7 * WT_STRIDE + oc], a);
            a = fmaf(t8, wb[8 * WT_STRIDE + oc], a);
            acc[oc] = a;
        }
    }

    if (g > 0) {
#pragma unroll
        for (int oc = 0; oc < AUXC; ++oc) red[g - 1][oc][px] = acc[oc];
    }
    __syncthreads();
    if (g == 0) {
        float* ap = aux + (size_t)b * AUXC * HWSZ + y * NW + px;
#pragma unroll
        for (int oc = 0; oc < AUXC; ++oc) {
            float s = acc[oc] + red[0][oc][px] + red[1][oc][px] + red[2][oc][px];
            if (oc < 18) {
                ap[oc * HWSZ] = s + offb[oc];
            } else {
                float z = s + modb[oc - 18];
                ap[oc * HWSZ] = 2.f / (1.f + __expf(-z));
            }
        }
    }
}

// ---------------------------------------------------------------------------
// Kernel 2: deformable sampling + MFMA, NHWC source, tap-major K, K-split x2.
// Block = 512 thr = 8 waves: wave -> n-tile (wv&3), K-half (wv>>2).
// K-dim kk = ktap*96 + c (tap-major): one K-step(32) has FIXED (ktap,px)
// geometry and 32 consecutive channels -> each lane loads 4x bf16x8 (16B)
// tap vectors instead of 32 scattered 2B loads; bilinear weights unpack once
// per step. 1-deep software prefetch of next step's geometry+taps.
// MFMA 16x16x32 bf16 layout (m89-verified): A[m=l&15][k=g*8+j],
// B[k][n=l&15], D col=l&15, row=g*4+r.
// ---------------------------------------------------------------------------
__global__ __launch_bounds__(512, 4) void deform_mfma_kernel(
    const unsigned short* __restrict__ xhwc,   // [b][yx][c] bf16
    const float* __restrict__ aux,             // (B,27,H,W)
    const unsigned short* __restrict__ wb16,   // [oc][ktap*96+c] bf16
    float* __restrict__ out)                   // (B,C,H,W) pre-BN
{
    __shared__ uint4 sA[NK][66];               // 4x u32 byte offsets (pix*192)
    __shared__ uint2 sW[NK][66];               // 4x bf16 bilinear*mask weights
    __shared__ float sRed[4][24][64];          // K-split reduction

    int t = threadIdx.x;
    int bid = blockIdx.x;
    int work = ((bid & 7) << 7) | (bid >> 3);  // bijective, 1024 wg
    int base = work * 64;
    int b = base >> 14;
    int rem0 = base & (HWSZ - 1);
    int y = rem0 >> 7;
    int x0 = rem0 & (NW - 1);                  // 0 or 64

    const float* auxb = aux + (size_t)b * AUXC * HWSZ;

    // ---- geometry: per (k, px): 4 clamped pixel byte-offsets + weights ----
    for (int e = t; e < 576; e += 512) {
        int px = e & 63;
        int k  = e >> 6;
        int xcol = x0 + px;
        int idx = y * NW + xcol;
        float offy = auxb[(2 * k) * HWSZ + idx];
        float offx = auxb[(2 * k + 1) * HWSZ + idx];
        float m    = auxb[(18 + k) * HWSZ + idx];
        int ky = k / 3, kx = k - 3 * (k / 3);
        float py  = (float)(y - 1 + ky) + offy;
        float pxf = (float)(xcol - 1 + kx) + offx;
        float y0f = floorf(py), x0f = floorf(pxf);
        float dy = py - y0f, dx = pxf - x0f;
        int iy0 = (int)y0f, ix0 = (int)x0f;
        int iy1 = iy0 + 1,  ix1 = ix0 + 1;

        bool vy0 = (iy0 >= 0) && (iy0 < NH);
        bool vy1 = (iy1 >= 0) && (iy1 < NH);
        bool vx0 = (ix0 >= 0) && (ix0 < NW);
        bool vx1 = (ix1 >= 0) && (ix1 < NW);
        int cy0 = min(max(iy0, 0), NH - 1);
        int cy1 = min(max(iy1, 0), NH - 1);
        int cx0 = min(max(ix0, 0), NW - 1);
        int cx1 = min(max(ix1, 0), NW - 1);

        float g00 = (1.f - dy) * (1.f - dx) * m; if (!(vy0 && vx0)) g00 = 0.f;
        float g01 = (1.f - dy) * dx * m;         if (!(vy0 && vx1)) g01 = 0.f;
        float g10 = dy * (1.f - dx) * m;         if (!(vy1 && vx0)) g10 = 0.f;
        float g11 = dy * dx * m;                 if (!(vy1 && vx1)) g11 = 0.f;

        uint4 ua;
        ua.x = (unsigned int)(cy0 * NW + cx0) * PIXB;
        ua.y = (unsigned int)(cy0 * NW + cx1) * PIXB;
        ua.z = (unsigned int)(cy1 * NW + cx0) * PIXB;
        ua.w = (unsigned int)(cy1 * NW + cx1) * PIXB;
        uint2 uw;
        uw.x = bf16r(g00) | (bf16r(g01) << 16);
        uw.y = bf16r(g10) | (bf16r(g11) << 16);
        sA[k][px] = ua;
        sW[k][px] = uw;
    }
    __syncthreads();

    f32x4 acc[6];
#pragma unroll
    for (int i = 0; i < 6; ++i) acc[i] = (f32x4){0.f, 0.f, 0.f, 0.f};

    const int lane15   = t & 15;
    const int g        = (t >> 4) & 3;         // k-subgroup within wave
    const int wv       = t >> 6;
    const int nt       = wv & 3;               // n-tile
    const int ks       = wv >> 2;              // K-split half
    const int px_local = (nt << 4) | lane15;
    const int g8       = g << 3;
    const int l64      = t & 63;

    const int stbeg = ks ? 14 : 0;             // 27 K-steps: 14 / 13
    const int stend = ks ? 27 : 14;

    const char* pB = (const char*)(xhwc + (size_t)b * HWSZ * NC);

    // ---- prologue: load step stbeg's geometry + tap vectors ----
    int st = stbeg;
    int k_ = st / 3;
    int c2 = ((st - 3 * k_) * 32 + g8) * 2;     // channel byte offset
    uint4 ga = sA[k_][px_local];
    uint2 gw = sW[k_][px_local];
    bf16x8 v0 = *(const bf16x8*)(pB + ga.x + c2);
    bf16x8 v1 = *(const bf16x8*)(pB + ga.y + c2);
    bf16x8 v2 = *(const bf16x8*)(pB + ga.z + c2);
    bf16x8 v3 = *(const bf16x8*)(pB + ga.w + c2);

    for (; st < stend; ++st) {
        // prefetch next step (wrap-safe; epilogue result unused)
        int stn = (st + 1 < stend) ? st + 1 : stbeg;
        int kn  = stn / 3;
        int c2n = ((stn - 3 * kn) * 32 + g8) * 2;
        uint4 gaN = sA[kn][px_local];
        uint2 gwN = sW[kn][px_local];
        bf16x8 n0 = *(const bf16x8*)(pB + gaN.x + c2n);
        bf16x8 n1 = *(const bf16x8*)(pB + gaN.y + c2n);
        bf16x8 n2 = *(const bf16x8*)(pB + gaN.z + c2n);
        bf16x8 n3 = *(const bf16x8*)(pB + gaN.w + c2n);

        // A fragments (L2-resident weights)
        bf16x8 afr[6];
#pragma unroll
        for (int i = 0; i < 6; ++i)
            afr[i] = *(const bf16x8*)(wb16 + (size_t)(i * 16 + lane15) * CKK + st * 32 + g8);

        // combine: weights uniform across the 8 channels of this step
        float w00 = uaf(gw.x << 16), w01 = uaf(gw.x & 0xffff0000u);
        float w10 = uaf(gw.y << 16), w11 = uaf(gw.y & 0xffff0000u);
        bf16x8 bfr;
#pragma unroll
        for (int j = 0; j < 8; ++j) {
            float f0 = uaf((unsigned int)(unsigned short)v0[j] << 16);
            float f1 = uaf((unsigned int)(unsigned short)v1[j] << 16);
            float f2 = uaf((unsigned int)(unsigned short)v2[j] << 16);
            float f3 = uaf((unsigned int)(unsigned short)v3[j] << 16);
            float s = f0 * w00;
            s = fmaf(f1, w01, s);
            s = fmaf(f2, w10, s);
            s = fmaf(f3, w11, s);
            bfr[j] = (short)bf16r(s);
        }

#pragma unroll
        for (int i = 0; i < 6; ++i)
            acc[i] = __builtin_amdgcn_mfma_f32_16x16x32_bf16(afr[i], bfr, acc[i], 0, 0, 0);

        ga = gaN; gw = gwN; v0 = n0; v1 = n1; v2 = n2; v3 = n3;
    }

    // ---- K-split reduce: upper half -> LDS, lower half adds & stores ----
    if (ks == 1) {
#pragma unroll
        for (int i = 0; i < 6; ++i)
#pragma unroll
            for (int r = 0; r < 4; ++r)
                sRed[nt][i * 4 + r][l64] = acc[i][r];
    }
    __syncthreads();
    if (ks == 0) {
        float* ob = out + (size_t)b * NC * HWSZ + y * NW + x0 + px_local;
#pragma unroll
        for (int i = 0; i < 6; ++i) {
            int row0 = i * 16 + g * 4;
#pragma unroll
            for (int r = 0; r < 4; ++r)
                ob[(row0 + r) * HWSZ] = acc[i][r] + sRed[nt][i * 4 + r][l64];
        }
    }
}

// ---------------------------------------------------------------------------
// Kernel 3a: per-(b,c) partial sums.  Kernel 3b: finalize scale/shift.
// ---------------------------------------------------------------------------
__global__ __launch_bounds__(256) void bnstats_kernel(
    const float* __restrict__ h, float* __restrict__ part)
{
    int bc = blockIdx.x;                 // 0..383 = b*NC+c
    const float4* p = (const float4*)(h + (size_t)bc * HWSZ);
    float s = 0.f, s2 = 0.f;
    for (int i = threadIdx.x; i < HWSZ / 4; i += 256) {
        float4 v = p[i];
        s  += v.x + v.y + v.z + v.w;
        s2 += v.x * v.x + v.y * v.y + v.z * v.z + v.w * v.w;
    }
#pragma unroll
    for (int o = 32; o > 0; o >>= 1) {
        s  += __shfl_down(s, o);
        s2 += __shfl_down(s2, o);
    }
    __shared__ float red[8];
    int wv = threadIdx.x >> 6, ln = threadIdx.x & 63;
    if (ln == 0) { red[wv] = s; red[4 + wv] = s2; }
    __syncthreads();
    if (threadIdx.x == 0) {
        part[bc]            = red[0] + red[1] + red[2] + red[3];
        part[NB * NC + bc]  = red[4] + red[5] + red[6] + red[7];
    }
}

__global__ __launch_bounds__(128) void bnfinalize_kernel(
    const float* __restrict__ part, const float* __restrict__ g,
    const float* __restrict__ bt, float* __restrict__ sc)
{
    int c = threadIdx.x;
    if (c >= NC) return;
    float s = 0.f, s2 = 0.f;
#pragma unroll
    for (int b = 0; b < NB; ++b) {
        s  += part[b * NC + c];
        s2 += part[NB * NC + b * NC + c];
    }
    const float inv_n = 1.f / (float)(NB * HWSZ);
    float mean = s * inv_n;
    float var  = s2 * inv_n - mean * mean;
    float scale = g[c] * rsqrtf(var + 1e-5f);
    sc[c] = scale;
    sc[NC + c] = bt[c] - mean * scale;
}

// ---------------------------------------------------------------------------
// Kernel 4: BN + leaky ReLU in place
// ---------------------------------------------------------------------------
__global__ __launch_bounds__(256) void bnlrelu_kernel(
    float* __restrict__ h, const float* __restrict__ sc)
{
    const int n4 = NB * NC * HWSZ / 4;
    for (int i = blockIdx.x * 256 + threadIdx.x; i < n4; i += gridDim.x * 256) {
        int c = (i >> 12) % NC;
        float scale = sc[c], shift = sc[NC + c];
        float4 v = ((const float4*)h)[i];
        float4 o;
        o.x = fmaf(scale, v.x, shift); o.x = o.x >= 0.f ? o.x : 0.1f * o.x;
        o.y = fmaf(scale, v.y, shift); o.y = o.y >= 0.f ? o.y : 0.1f * o.y;
        o.z = fmaf(scale, v.z, shift); o.z = o.z >= 0.f ? o.z : 0.1f * o.z;
        o.w = fmaf(scale, v.w, shift); o.w = o.w >= 0.f ? o.w : 0.1f * o.w;
        ((float4*)h)[i] = o;
    }
}

// ---------------------------------------------------------------------------
// Kernel 5: out = x + BN(out_raw) in place
// ---------------------------------------------------------------------------
__global__ __launch_bounds__(256) void final_kernel(
    float* __restrict__ out, const float* __restrict__ x,
    const float* __restrict__ sc)
{
    const int n4 = NB * NC * HWSZ / 4;
    for (int i = blockIdx.x * 256 + threadIdx.x; i < n4; i += gridDim.x * 256) {
        int c = (i >> 12) % NC;
        float scale = sc[c], shift = sc[NC + c];
        float4 v = ((const float4*)out)[i];
        float4 xv = ((const float4*)x)[i];
        float4 o;
        o.x = xv.x + fmaf(scale, v.x, shift);
        o.y = xv.y + fmaf(scale, v.y, shift);
        o.z = xv.z + fmaf(scale, v.z, shift);
        o.w = xv.w + fmaf(scale, v.w, shift);
        ((float4*)out)[i] = o;
    }
}

// ---------------------------------------------------------------------------
extern "C" void kernel_launch(void* const* d_in, const int* in_sizes, int n_in,
                              void* d_out, int out_size, void* d_ws, size_t ws_size,
                              hipStream_t stream)
{
    const float* x        = (const float*)d_in[0];
    const float* d1_off_w = (const float*)d_in[1];
    const float* d1_off_b = (const float*)d_in[2];
    const float* d1_mod_w = (const float*)d_in[3];
    const float* d1_mod_b = (const float*)d_in[4];
    const float* d1_w     = (const float*)d_in[5];
    const float* d2_off_w = (const float*)d_in[6];
    const float* d2_off_b = (const float*)d_in[7];
    const float* d2_mod_w = (const float*)d_in[8];
    const float* d2_mod_b = (const float*)d_in[9];
    const float* d2_w     = (const float*)d_in[10];
    const float* bn_g     = (const float*)d_in[11];
    const float* bn_b     = (const float*)d_in[12];
    float* out = (float*)d_out;

    // ws layout (floats): h1 | aux | wT | wb16 | sc | part | xhwc(bf16)
    const size_t nImg = (size_t)NB * NC * HWSZ;       // 6291456
    float* h1   = (float*)d_ws;
    float* aux  = h1   + nImg;
    float* wT   = aux  + (size_t)NB * AUXC * HWSZ;
    unsigned short* wb16 = (unsigned short*)(wT + WT_ELEMS);
    float* sc   = wT + WT_ELEMS + WB_ELEMS / 2;
    float* part = sc + 2 * NC;
    unsigned short* xhwc = (unsigned short*)(part + 2 * NB * NC);

    const int npix = NB * HWSZ;                       // 65536
    const int prep_blocks = (WT_ELEMS + WB_ELEMS + 255) / 256;

    // ---- layer 1 ----
    prep_weights_kernel<<<prep_blocks, 256, 0, stream>>>(d1_off_w, d1_mod_w, d1_w, wT, wb16);
    conv27_kernel<<<NB * NH, 512, 0, stream>>>(x, wT, d1_off_b, d1_mod_b, aux);
    nhwc_kernel<<<npix / 64, 256, 0, stream>>>(x, xhwc);
    deform_mfma_kernel<<<npix / 64, 512, 0, stream>>>(xhwc, aux, wb16, h1);
    bnstats_kernel<<<NB * NC, 256, 0, stream>>>(h1, part);
    bnfinalize_kernel<<<1, 128, 0, stream>>>(part, bn_g, bn_b, sc);
    bnlrelu_kernel<<<2048, 256, 0, stream>>>(h1, sc);

    // ---- layer 2 ----
    prep_weights_kernel<<<prep_blocks, 256, 0, stream>>>(d2_off_w, d2_mod_w, d2_w, wT, wb16);
    conv27_kernel<<<NB * NH, 512, 0, stream>>>(h1, wT, d2_off_b, d2_mod_b, aux);
    nhwc_kernel<<<npix / 64, 256, 0, stream>>>(h1, xhwc);
    deform_mfma_kernel<<<npix / 64, 512, 0, stream>>>(xhwc, aux, wb16, out);
    bnstats_kernel<<<NB * NC, 256, 0, stream>>>(out, part);
    bnfinalize_kernel<<<1, 128, 0, stream>>>(part, bn_g, bn_b, sc);
    final_kernel<<<2048, 256, 0, stream>>>(out, x, sc);
}

// Round 8
// 255.795 us; speedup vs baseline: 3.1904x; 2.2004x over previous
//
#include <hip/hip_runtime.h>
#include <math.h>

#define NB 4
#define NC 96
#define NH 128
#define NW 128
#define HWSZ (NH * NW)          // 16384
#define NK 9
#define AUXC 27                 // 18 offset + 9 mask channels
#define CKK (NC * NK)           // 864
#define WC_ELEMS (32 * CKK)     // 27648 bf16 conv27 weights (27 used + 5 zero)
#define WB_ELEMS (NC * CKK)     // 82944 bf16 deform weights
#define PIXB (NC * 2)           // 192 bytes per NHWC pixel record
#define ZOFF ((unsigned int)(NB * HWSZ * PIXB))   // zero-record byte offset

typedef __attribute__((ext_vector_type(8))) short bf16x8;
typedef __attribute__((ext_vector_type(4))) float f32x4;

__device__ __forceinline__ unsigned int bf16r(float f) {
    unsigned int u = __float_as_uint(f);
    u += 0x7fffu + ((u >> 16) & 1u);
    return u >> 16;                      // RNE bf16 bits
}
__device__ __forceinline__ float uaf(unsigned int u) { return __uint_as_float(u); }

// ---------------------------------------------------------------------------
// Kernel 0: weight prep (all bf16, tap-major K: kk = tap*96 + c).
//   wc16[oc*864 + tap*96 + c]  oc<18: offw, 18..26: modw, 27..31: zero
//   wb16[oc*864 + tap*96 + c]  deform weights
// ---------------------------------------------------------------------------
__global__ __launch_bounds__(256) void prep_weights_kernel(
    const float* __restrict__ offw, const float* __restrict__ modw,
    const float* __restrict__ w,
    unsigned short* __restrict__ wc16, unsigned short* __restrict__ wb16)
{
    int idx = blockIdx.x * 256 + threadIdx.x;
    if (idx < WC_ELEMS) {
        int oc  = idx / CKK;
        int rem = idx - oc * CKK;           // tap*96 + c
        int tap = rem / NC;
        int c   = rem - tap * NC;
        float v = 0.f;
        if (oc < 18)      v = offw[oc * CKK + c * NK + tap];
        else if (oc < 27) v = modw[(oc - 18) * CKK + c * NK + tap];
        wc16[idx] = (unsigned short)bf16r(v);
    }
    int j = idx - WC_ELEMS;
    if (j >= 0 && j < WB_ELEMS) {
        int oc   = j / CKK;
        int rem  = j - oc * CKK;
        int ktap = rem / NC;
        int c    = rem - ktap * NC;
        wb16[j] = (unsigned short)bf16r(w[oc * CKK + c * NK + ktap]);
    }
}

// ---------------------------------------------------------------------------
// Kernel 0b: NCHW f32 -> NHWC bf16 transpose + zero-record init.
// Block: 256 thr, tile = 64 px x 96 ch. Grid = NB*HWSZ/64 = 1024.
// ---------------------------------------------------------------------------
__global__ __launch_bounds__(256) void nhwc_kernel(
    const float* __restrict__ in, unsigned short* __restrict__ o)
{
    __shared__ unsigned short tile[64][98];     // pad 96->98 (bank spread)
    int t = threadIdx.x;
    int blk = blockIdx.x;
    int b  = blk >> 8;
    int p0 = (blk & 255) * 64;

    if (blk == 0 && t < NC) o[(size_t)NB * HWSZ * NC + t] = 0;  // zero record

    const float* ib = in + (size_t)b * NC * HWSZ + p0;

    // read: e = c*64 + px, float2 along px
#pragma unroll
    for (int r = 0; r < 12; ++r) {
        int e = (r * 256 + t) * 2;
        int c = e >> 6, px = e & 63;
        float2 v = *(const float2*)(ib + c * HWSZ + px);
        tile[px][c]     = (unsigned short)bf16r(v.x);
        tile[px + 1][c] = (unsigned short)bf16r(v.y);
    }
    __syncthreads();

    // write: e = px*96 + c, ushort2 along c
    unsigned short* ob = o + ((size_t)b * HWSZ + p0) * NC;
#pragma unroll
    for (int r = 0; r < 12; ++r) {
        int e = (r * 256 + t) * 2;
        int px = e / 96, c = e - px * 96;
        ushort2 u;
        u.x = tile[px][c];
        u.y = tile[px][c + 1];
        *(ushort2*)(ob + e) = u;
    }
}

// ---------------------------------------------------------------------------
// Kernel 1: conv27 as MFMA GEMM. M=32(27) oc x N=64 px x K=864 (tap-major).
// Same skeleton as deform_mfma: 8 waves, n-tile=(wv&3), K-split=(wv>>2),
// 1-deep prefetch, XCD swizzle. B-fragment = raw bf16x8 NHWC load (no
// combine); zero-padding via zero record. Epilogue: +bias / 2*sigmoid,
// writes NCHW fp32 aux planes.
// ---------------------------------------------------------------------------
__global__ __launch_bounds__(512, 4) void conv27_mfma_kernel(
    const unsigned short* __restrict__ xhwc,   // [b][yx][c] bf16 (+zero rec)
    const unsigned short* __restrict__ wc16,   // [32][tap*96+c] bf16
    const float* __restrict__ offb, const float* __restrict__ modb,
    float* __restrict__ aux)                   // (B,27,H,W) fp32
{
    __shared__ unsigned int sOff[NK][66];
    __shared__ float sRed[4][8][64];

    int t = threadIdx.x;
    int bid = blockIdx.x;
    int work = ((bid & 7) << 7) | (bid >> 3);  // bijective, 1024 wg
    int base = work * 64;
    int b = base >> 14;
    int rem0 = base & (HWSZ - 1);
    int y = rem0 >> 7;
    int x0 = rem0 & (NW - 1);

    // geometry: per (tap, px) absolute byte offset (zero record if invalid)
    for (int e = t; e < 576; e += 512) {
        int px = e & 63, k = e >> 6;
        int ky = k / 3, kx = k - 3 * (k / 3);
        int yy = y + ky - 1, xx = x0 + px + kx - 1;
        bool v = (yy >= 0) && (yy < NH) && (xx >= 0) && (xx < NW);
        sOff[k][px] = v ? (unsigned int)(((b << 14) + yy * NW + xx) * PIXB)
                        : ZOFF;
    }
    __syncthreads();

    f32x4 acc[2];
    acc[0] = (f32x4){0.f, 0.f, 0.f, 0.f};
    acc[1] = (f32x4){0.f, 0.f, 0.f, 0.f};

    const int lane15   = t & 15;
    const int g        = (t >> 4) & 3;
    const int wv       = t >> 6;
    const int nt       = wv & 3;
    const int ks       = wv >> 2;
    const int px_local = (nt << 4) | lane15;
    const int g8       = g << 3;
    const int l64      = t & 63;

    const int stbeg = ks ? 14 : 0;             // 27 K-steps: 14 / 13
    const int stend = ks ? 27 : 14;

    const char* pB = (const char*)xhwc;

    // prologue
    int st = stbeg;
    int tap = st / 3;
    int c2  = ((st - 3 * tap) * 32 + g8) * 2;
    bf16x8 bfr = *(const bf16x8*)(pB + sOff[tap][px_local] + c2);

    for (; st < stend; ++st) {
        int stn  = (st + 1 < stend) ? st + 1 : stbeg;
        int tapn = stn / 3;
        int c2n  = ((stn - 3 * tapn) * 32 + g8) * 2;
        bf16x8 bn = *(const bf16x8*)(pB + sOff[tapn][px_local] + c2n);

        bf16x8 a0 = *(const bf16x8*)(wc16 + (size_t)lane15 * CKK + st * 32 + g8);
        bf16x8 a1 = *(const bf16x8*)(wc16 + (size_t)(16 + lane15) * CKK + st * 32 + g8);

        acc[0] = __builtin_amdgcn_mfma_f32_16x16x32_bf16(a0, bfr, acc[0], 0, 0, 0);
        acc[1] = __builtin_amdgcn_mfma_f32_16x16x32_bf16(a1, bfr, acc[1], 0, 0, 0);
        bfr = bn;
    }

    if (ks == 1) {
#pragma unroll
        for (int i = 0; i < 2; ++i)
#pragma unroll
            for (int r = 0; r < 4; ++r)
                sRed[nt][i * 4 + r][l64] = acc[i][r];
    }
    __syncthreads();
    if (ks == 0) {
        float* ap = aux + (size_t)b * AUXC * HWSZ + y * NW + x0 + px_local;
#pragma unroll
        for (int i = 0; i < 2; ++i) {
#pragma unroll
            for (int r = 0; r < 4; ++r) {
                int oc = i * 16 + g * 4 + r;
                float v = acc[i][r] + sRed[nt][i * 4 + r][l64];
                if (oc < 18) {
                    ap[oc * HWSZ] = v + offb[oc];
                } else if (oc < AUXC) {
                    float z = v + modb[oc - 18];
                    ap[oc * HWSZ] = 2.f / (1.f + __expf(-z));
                }
            }
        }
    }
}

// ---------------------------------------------------------------------------
// Kernel 2: deformable sampling + MFMA (unchanged from round 7).
// ---------------------------------------------------------------------------
__global__ __launch_bounds__(512, 4) void deform_mfma_kernel(
    const unsigned short* __restrict__ xhwc,   // [b][yx][c] bf16
    const float* __restrict__ aux,             // (B,27,H,W)
    const unsigned short* __restrict__ wb16,   // [oc][ktap*96+c] bf16
    float* __restrict__ out)                   // (B,C,H,W) pre-BN
{
    __shared__ uint4 sA[NK][66];
    __shared__ uint2 sW[NK][66];
    __shared__ float sRed[4][24][64];

    int t = threadIdx.x;
    int bid = blockIdx.x;
    int work = ((bid & 7) << 7) | (bid >> 3);
    int base = work * 64;
    int b = base >> 14;
    int rem0 = base & (HWSZ - 1);
    int y = rem0 >> 7;
    int x0 = rem0 & (NW - 1);

    const float* auxb = aux + (size_t)b * AUXC * HWSZ;

    for (int e = t; e < 576; e += 512) {
        int px = e & 63;
        int k  = e >> 6;
        int xcol = x0 + px;
        int idx = y * NW + xcol;
        float offy = auxb[(2 * k) * HWSZ + idx];
        float offx = auxb[(2 * k + 1) * HWSZ + idx];
        float m    = auxb[(18 + k) * HWSZ + idx];
        int ky = k / 3, kx = k - 3 * (k / 3);
        float py  = (float)(y - 1 + ky) + offy;
        float pxf = (float)(xcol - 1 + kx) + offx;
        float y0f = floorf(py), x0f = floorf(pxf);
        float dy = py - y0f, dx = pxf - x0f;
        int iy0 = (int)y0f, ix0 = (int)x0f;
        int iy1 = iy0 + 1,  ix1 = ix0 + 1;

        bool vy0 = (iy0 >= 0) && (iy0 < NH);
        bool vy1 = (iy1 >= 0) && (iy1 < NH);
        bool vx0 = (ix0 >= 0) && (ix0 < NW);
        bool vx1 = (ix1 >= 0) && (ix1 < NW);
        int cy0 = min(max(iy0, 0), NH - 1);
        int cy1 = min(max(iy1, 0), NH - 1);
        int cx0 = min(max(ix0, 0), NW - 1);
        int cx1 = min(max(ix1, 0), NW - 1);

        float g00 = (1.f - dy) * (1.f - dx) * m; if (!(vy0 && vx0)) g00 = 0.f;
        float g01 = (1.f - dy) * dx * m;         if (!(vy0 && vx1)) g01 = 0.f;
        float g10 = dy * (1.f - dx) * m;         if (!(vy1 && vx0)) g10 = 0.f;
        float g11 = dy * dx * m;                 if (!(vy1 && vx1)) g11 = 0.f;

        uint4 ua;
        ua.x = (unsigned int)(cy0 * NW + cx0) * PIXB;
        ua.y = (unsigned int)(cy0 * NW + cx1) * PIXB;
        ua.z = (unsigned int)(cy1 * NW + cx0) * PIXB;
        ua.w = (unsigned int)(cy1 * NW + cx1) * PIXB;
        uint2 uw;
        uw.x = bf16r(g00) | (bf16r(g01) << 16);
        uw.y = bf16r(g10) | (bf16r(g11) << 16);
        sA[k][px] = ua;
        sW[k][px] = uw;
    }
    __syncthreads();

    f32x4 acc[6];
#pragma unroll
    for (int i = 0; i < 6; ++i) acc[i] = (f32x4){0.f, 0.f, 0.f, 0.f};

    const int lane15   = t & 15;
    const int g        = (t >> 4) & 3;
    const int wv       = t >> 6;
    const int nt       = wv & 3;
    const int ks       = wv >> 2;
    const int px_local = (nt << 4) | lane15;
    const int g8       = g << 3;
    const int l64      = t & 63;

    const int stbeg = ks ? 14 : 0;
    const int stend = ks ? 27 : 14;

    const char* pB = (const char*)(xhwc + (size_t)b * HWSZ * NC);

    int st = stbeg;
    int k_ = st / 3;
    int c2 = ((st - 3 * k_) * 32 + g8) * 2;
    uint4 ga = sA[k_][px_local];
    uint2 gw = sW[k_][px_local];
    bf16x8 v0 = *(const bf16x8*)(pB + ga.x + c2);
    bf16x8 v1 = *(const bf16x8*)(pB + ga.y + c2);
    bf16x8 v2 = *(const bf16x8*)(pB + ga.z + c2);
    bf16x8 v3 = *(const bf16x8*)(pB + ga.w + c2);

    for (; st < stend; ++st) {
        int stn = (st + 1 < stend) ? st + 1 : stbeg;
        int kn  = stn / 3;
        int c2n = ((stn - 3 * kn) * 32 + g8) * 2;
        uint4 gaN = sA[kn][px_local];
        uint2 gwN = sW[kn][px_local];
        bf16x8 n0 = *(const bf16x8*)(pB + gaN.x + c2n);
        bf16x8 n1 = *(const bf16x8*)(pB + gaN.y + c2n);
        bf16x8 n2 = *(const bf16x8*)(pB + gaN.z + c2n);
        bf16x8 n3 = *(const bf16x8*)(pB + gaN.w + c2n);

        bf16x8 afr[6];
#pragma unroll
        for (int i = 0; i < 6; ++i)
            afr[i] = *(const bf16x8*)(wb16 + (size_t)(i * 16 + lane15) * CKK + st * 32 + g8);

        float w00 = uaf(gw.x << 16), w01 = uaf(gw.x & 0xffff0000u);
        float w10 = uaf(gw.y << 16), w11 = uaf(gw.y & 0xffff0000u);
        bf16x8 bfr;
#pragma unroll
        for (int j = 0; j < 8; ++j) {
            float f0 = uaf((unsigned int)(unsigned short)v0[j] << 16);
            float f1 = uaf((unsigned int)(unsigned short)v1[j] << 16);
            float f2 = uaf((unsigned int)(unsigned short)v2[j] << 16);
            float f3 = uaf((unsigned int)(unsigned short)v3[j] << 16);
            float s = f0 * w00;
            s = fmaf(f1, w01, s);
            s = fmaf(f2, w10, s);
            s = fmaf(f3, w11, s);
            bfr[j] = (short)bf16r(s);
        }

#pragma unroll
        for (int i = 0; i < 6; ++i)
            acc[i] = __builtin_amdgcn_mfma_f32_16x16x32_bf16(afr[i], bfr, acc[i], 0, 0, 0);

        ga = gaN; gw = gwN; v0 = n0; v1 = n1; v2 = n2; v3 = n3;
    }

    if (ks == 1) {
#pragma unroll
        for (int i = 0; i < 6; ++i)
#pragma unroll
            for (int r = 0; r < 4; ++r)
                sRed[nt][i * 4 + r][l64] = acc[i][r];
    }
    __syncthreads();
    if (ks == 0) {
        float* ob = out + (size_t)b * NC * HWSZ + y * NW + x0 + px_local;
#pragma unroll
        for (int i = 0; i < 6; ++i) {
            int row0 = i * 16 + g * 4;
#pragma unroll
            for (int r = 0; r < 4; ++r)
                ob[(row0 + r) * HWSZ] = acc[i][r] + sRed[nt][i * 4 + r][l64];
        }
    }
}

// ---------------------------------------------------------------------------
// Kernel 3a: per-(b,c) partial sums.  Kernel 3b: finalize scale/shift.
// ---------------------------------------------------------------------------
__global__ __launch_bounds__(256) void bnstats_kernel(
    const float* __restrict__ h, float* __restrict__ part)
{
    int bc = blockIdx.x;
    const float4* p = (const float4*)(h + (size_t)bc * HWSZ);
    float s = 0.f, s2 = 0.f;
    for (int i = threadIdx.x; i < HWSZ / 4; i += 256) {
        float4 v = p[i];
        s  += v.x + v.y + v.z + v.w;
        s2 += v.x * v.x + v.y * v.y + v.z * v.z + v.w * v.w;
    }
#pragma unroll
    for (int o = 32; o > 0; o >>= 1) {
        s  += __shfl_down(s, o);
        s2 += __shfl_down(s2, o);
    }
    __shared__ float red[8];
    int wv = threadIdx.x >> 6, ln = threadIdx.x & 63;
    if (ln == 0) { red[wv] = s; red[4 + wv] = s2; }
    __syncthreads();
    if (threadIdx.x == 0) {
        part[bc]            = red[0] + red[1] + red[2] + red[3];
        part[NB * NC + bc]  = red[4] + red[5] + red[6] + red[7];
    }
}

__global__ __launch_bounds__(128) void bnfinalize_kernel(
    const float* __restrict__ part, const float* __restrict__ g,
    const float* __restrict__ bt, float* __restrict__ sc)
{
    int c = threadIdx.x;
    if (c >= NC) return;
    float s = 0.f, s2 = 0.f;
#pragma unroll
    for (int b = 0; b < NB; ++b) {
        s  += part[b * NC + c];
        s2 += part[NB * NC + b * NC + c];
    }
    const float inv_n = 1.f / (float)(NB * HWSZ);
    float mean = s * inv_n;
    float var  = s2 * inv_n - mean * mean;
    float scale = g[c] * rsqrtf(var + 1e-5f);
    sc[c] = scale;
    sc[NC + c] = bt[c] - mean * scale;
}

// ---------------------------------------------------------------------------
// Kernel 4: BN + leaky ReLU in place
// ---------------------------------------------------------------------------
__global__ __launch_bounds__(256) void bnlrelu_kernel(
    float* __restrict__ h, const float* __restrict__ sc)
{
    const int n4 = NB * NC * HWSZ / 4;
    for (int i = blockIdx.x * 256 + threadIdx.x; i < n4; i += gridDim.x * 256) {
        int c = (i >> 12) % NC;
        float scale = sc[c], shift = sc[NC + c];
        float4 v = ((const float4*)h)[i];
        float4 o;
        o.x = fmaf(scale, v.x, shift); o.x = o.x >= 0.f ? o.x : 0.1f * o.x;
        o.y = fmaf(scale, v.y, shift); o.y = o.y >= 0.f ? o.y : 0.1f * o.y;
        o.z = fmaf(scale, v.z, shift); o.z = o.z >= 0.f ? o.z : 0.1f * o.z;
        o.w = fmaf(scale, v.w, shift); o.w = o.w >= 0.f ? o.w : 0.1f * o.w;
        ((float4*)h)[i] = o;
    }
}

// ---------------------------------------------------------------------------
// Kernel 5: out = x + BN(out_raw) in place
// ---------------------------------------------------------------------------
__global__ __launch_bounds__(256) void final_kernel(
    float* __restrict__ out, const float* __restrict__ x,
    const float* __restrict__ sc)
{
    const int n4 = NB * NC * HWSZ / 4;
    for (int i = blockIdx.x * 256 + threadIdx.x; i < n4; i += gridDim.x * 256) {
        int c = (i >> 12) % NC;
        float scale = sc[c], shift = sc[NC + c];
        float4 v = ((const float4*)out)[i];
        float4 xv = ((const float4*)x)[i];
        float4 o;
        o.x = xv.x + fmaf(scale, v.x, shift);
        o.y = xv.y + fmaf(scale, v.y, shift);
        o.z = xv.z + fmaf(scale, v.z, shift);
        o.w = xv.w + fmaf(scale, v.w, shift);
        ((float4*)out)[i] = o;
    }
}

// ---------------------------------------------------------------------------
extern "C" void kernel_launch(void* const* d_in, const int* in_sizes, int n_in,
                              void* d_out, int out_size, void* d_ws, size_t ws_size,
                              hipStream_t stream)
{
    const float* x        = (const float*)d_in[0];
    const float* d1_off_w = (const float*)d_in[1];
    const float* d1_off_b = (const float*)d_in[2];
    const float* d1_mod_w = (const float*)d_in[3];
    const float* d1_mod_b = (const float*)d_in[4];
    const float* d1_w     = (const float*)d_in[5];
    const float* d2_off_w = (const float*)d_in[6];
    const float* d2_off_b = (const float*)d_in[7];
    const float* d2_mod_w = (const float*)d_in[8];
    const float* d2_mod_b = (const float*)d_in[9];
    const float* d2_w     = (const float*)d_in[10];
    const float* bn_g     = (const float*)d_in[11];
    const float* bn_b     = (const float*)d_in[12];
    float* out = (float*)d_out;

    // ws layout (floats): h1 | aux | wc16 | wb16 | sc | part | xhwc(+zero rec)
    const size_t nImg = (size_t)NB * NC * HWSZ;       // 6291456
    float* h1   = (float*)d_ws;
    float* aux  = h1   + nImg;
    unsigned short* wc16 = (unsigned short*)(aux + (size_t)NB * AUXC * HWSZ);
    unsigned short* wb16 = wc16 + WC_ELEMS;
    float* sc   = (float*)(wb16 + WB_ELEMS);
    float* part = sc + 2 * NC;
    unsigned short* xhwc = (unsigned short*)(part + 2 * NB * NC);

    const int npix = NB * HWSZ;                       // 65536
    const int prep_blocks = (WC_ELEMS + WB_ELEMS + 255) / 256;   // 432

    // ---- layer 1 ----
    prep_weights_kernel<<<prep_blocks, 256, 0, stream>>>(d1_off_w, d1_mod_w, d1_w, wc16, wb16);
    nhwc_kernel<<<npix / 64, 256, 0, stream>>>(x, xhwc);
    conv27_mfma_kernel<<<npix / 64, 512, 0, stream>>>(xhwc, wc16, d1_off_b, d1_mod_b, aux);
    deform_mfma_kernel<<<npix / 64, 512, 0, stream>>>(xhwc, aux, wb16, h1);
    bnstats_kernel<<<NB * NC, 256, 0, stream>>>(h1, part);
    bnfinalize_kernel<<<1, 128, 0, stream>>>(part, bn_g, bn_b, sc);
    bnlrelu_kernel<<<2048, 256, 0, stream>>>(h1, sc);

    // ---- layer 2 ----
    prep_weights_kernel<<<prep_blocks, 256, 0, stream>>>(d2_off_w, d2_mod_w, d2_w, wc16, wb16);
    nhwc_kernel<<<npix / 64, 256, 0, stream>>>(h1, xhwc);
    conv27_mfma_kernel<<<npix / 64, 512, 0, stream>>>(xhwc, wc16, d2_off_b, d2_mod_b, aux);
    deform_mfma_kernel<<<npix / 64, 512, 0, stream>>>(xhwc, aux, wb16, out);
    bnstats_kernel<<<NB * NC, 256, 0, stream>>>(out, part);
    bnfinalize_kernel<<<1, 128, 0, stream>>>(part, bn_g, bn_b, sc);
    final_kernel<<<2048, 256, 0, stream>>>(out, x, sc);
}

// Round 9
// 246.622 us; speedup vs baseline: 3.3091x; 1.0372x over previous
//
#include <hip/hip_runtime.h>
#include <math.h>

#define NB 4
#define NC 96
#define NH 128
#define NW 128
#define HWSZ (NH * NW)          // 16384
#define NK 9
#define AUXC 27                 // 18 offset + 9 mask channels
#define CKK (NC * NK)           // 864
#define WC_ELEMS (32 * CKK)     // 27648 bf16 conv27 weights (27 used + 5 zero)
#define WB_ELEMS (NC * CKK)     // 82944 bf16 deform weights
#define PIXB (NC * 2)           // 192 bytes per NHWC pixel record
#define ZOFF ((unsigned int)(NB * HWSZ * PIXB))   // zero-record byte offset

typedef __attribute__((ext_vector_type(8))) short bf16x8;
typedef __attribute__((ext_vector_type(4))) float f32x4;

__device__ __forceinline__ unsigned int bf16r(float f) {
    unsigned int u = __float_as_uint(f);
    u += 0x7fffu + ((u >> 16) & 1u);
    return u >> 16;                      // RNE bf16 bits
}
__device__ __forceinline__ float uaf(unsigned int u) { return __uint_as_float(u); }

// v_cvt_pk_bf16_f32: dst.lo = bf16(lo), dst.hi = bf16(hi); RNE == bf16r bits.
__device__ __forceinline__ unsigned int cvtpk(float lo, float hi) {
    unsigned int u;
    asm("v_cvt_pk_bf16_f32 %0, %1, %2" : "=v"(u) : "v"(lo), "v"(hi));
    return u;
}

// ---------------------------------------------------------------------------
// Kernel 0: weight prep (all bf16, tap-major K: kk = tap*96 + c).
// ---------------------------------------------------------------------------
__global__ __launch_bounds__(256) void prep_weights_kernel(
    const float* __restrict__ offw, const float* __restrict__ modw,
    const float* __restrict__ w,
    unsigned short* __restrict__ wc16, unsigned short* __restrict__ wb16)
{
    int idx = blockIdx.x * 256 + threadIdx.x;
    if (idx < WC_ELEMS) {
        int oc  = idx / CKK;
        int rem = idx - oc * CKK;           // tap*96 + c
        int tap = rem / NC;
        int c   = rem - tap * NC;
        float v = 0.f;
        if (oc < 18)      v = offw[oc * CKK + c * NK + tap];
        else if (oc < 27) v = modw[(oc - 18) * CKK + c * NK + tap];
        wc16[idx] = (unsigned short)bf16r(v);
    }
    int j = idx - WC_ELEMS;
    if (j >= 0 && j < WB_ELEMS) {
        int oc   = j / CKK;
        int rem  = j - oc * CKK;
        int ktap = rem / NC;
        int c    = rem - ktap * NC;
        wb16[j] = (unsigned short)bf16r(w[oc * CKK + c * NK + ktap]);
    }
}

// ---------------------------------------------------------------------------
// Kernel 0b: NCHW f32 -> NHWC bf16 transpose + zero-record init. (layer 1)
// ---------------------------------------------------------------------------
__global__ __launch_bounds__(256) void nhwc_kernel(
    const float* __restrict__ in, unsigned short* __restrict__ o)
{
    __shared__ unsigned short tile[64][98];
    int t = threadIdx.x;
    int blk = blockIdx.x;
    int b  = blk >> 8;
    int p0 = (blk & 255) * 64;

    if (blk == 0 && t < NC) o[(size_t)NB * HWSZ * NC + t] = 0;  // zero record

    const float* ib = in + (size_t)b * NC * HWSZ + p0;
#pragma unroll
    for (int r = 0; r < 12; ++r) {
        int e = (r * 256 + t) * 2;
        int c = e >> 6, px = e & 63;
        float2 v = *(const float2*)(ib + c * HWSZ + px);
        tile[px][c]     = (unsigned short)bf16r(v.x);
        tile[px + 1][c] = (unsigned short)bf16r(v.y);
    }
    __syncthreads();

    unsigned short* ob = o + ((size_t)b * HWSZ + p0) * NC;
#pragma unroll
    for (int r = 0; r < 12; ++r) {
        int e = (r * 256 + t) * 2;
        int px = e / 96, c = e - px * 96;
        ushort2 u;
        u.x = tile[px][c];
        u.y = tile[px][c + 1];
        *(ushort2*)(ob + e) = u;
    }
}

// ---------------------------------------------------------------------------
// Kernel 0c: fused BN + leakyReLU + NCHW->NHWC bf16 (layer 2 input).
// Produces bitwise the same xhwc as (bnlrelu; nhwc) did.
// ---------------------------------------------------------------------------
__global__ __launch_bounds__(256) void nhwcbn_kernel(
    const float* __restrict__ in, const float* __restrict__ sc,
    unsigned short* __restrict__ o)
{
    __shared__ unsigned short tile[64][98];
    int t = threadIdx.x;
    int blk = blockIdx.x;
    int b  = blk >> 8;
    int p0 = (blk & 255) * 64;

    const float* ib = in + (size_t)b * NC * HWSZ + p0;
#pragma unroll
    for (int r = 0; r < 12; ++r) {
        int e = (r * 256 + t) * 2;
        int c = e >> 6, px = e & 63;
        float scale = sc[c], shift = sc[NC + c];
        float2 v = *(const float2*)(ib + c * HWSZ + px);
        float ox = fmaf(scale, v.x, shift); ox = ox >= 0.f ? ox : 0.1f * ox;
        float oy = fmaf(scale, v.y, shift); oy = oy >= 0.f ? oy : 0.1f * oy;
        tile[px][c]     = (unsigned short)bf16r(ox);
        tile[px + 1][c] = (unsigned short)bf16r(oy);
    }
    __syncthreads();

    unsigned short* ob = o + ((size_t)b * HWSZ + p0) * NC;
#pragma unroll
    for (int r = 0; r < 12; ++r) {
        int e = (r * 256 + t) * 2;
        int px = e / 96, c = e - px * 96;
        ushort2 u;
        u.x = tile[px][c];
        u.y = tile[px][c + 1];
        *(ushort2*)(ob + e) = u;
    }
}

// ---------------------------------------------------------------------------
// Kernel 1: conv27 as MFMA GEMM, now with 1-deep A-fragment prefetch.
// ---------------------------------------------------------------------------
__global__ __launch_bounds__(512, 4) void conv27_mfma_kernel(
    const unsigned short* __restrict__ xhwc,
    const unsigned short* __restrict__ wc16,
    const float* __restrict__ offb, const float* __restrict__ modb,
    float* __restrict__ aux)
{
    __shared__ unsigned int sOff[NK][66];
    __shared__ float sRed[4][8][64];

    int t = threadIdx.x;
    int bid = blockIdx.x;
    int work = ((bid & 7) << 7) | (bid >> 3);
    int base = work * 64;
    int b = base >> 14;
    int rem0 = base & (HWSZ - 1);
    int y = rem0 >> 7;
    int x0 = rem0 & (NW - 1);

    for (int e = t; e < 576; e += 512) {
        int px = e & 63, k = e >> 6;
        int ky = k / 3, kx = k - 3 * (k / 3);
        int yy = y + ky - 1, xx = x0 + px + kx - 1;
        bool v = (yy >= 0) && (yy < NH) && (xx >= 0) && (xx < NW);
        sOff[k][px] = v ? (unsigned int)(((b << 14) + yy * NW + xx) * PIXB)
                        : ZOFF;
    }
    __syncthreads();

    f32x4 acc[2];
    acc[0] = (f32x4){0.f, 0.f, 0.f, 0.f};
    acc[1] = (f32x4){0.f, 0.f, 0.f, 0.f};

    const int lane15   = t & 15;
    const int g        = (t >> 4) & 3;
    const int wv       = t >> 6;
    const int nt       = wv & 3;
    const int ks       = wv >> 2;
    const int px_local = (nt << 4) | lane15;
    const int g8       = g << 3;
    const int l64      = t & 63;

    const int stbeg = ks ? 14 : 0;
    const int stend = ks ? 27 : 14;

    const char* pB = (const char*)xhwc;

    // prologue: B and A fragments for stbeg
    int st = stbeg;
    int tap = st / 3;
    int c2  = ((st - 3 * tap) * 32 + g8) * 2;
    bf16x8 bfr = *(const bf16x8*)(pB + sOff[tap][px_local] + c2);
    bf16x8 a0  = *(const bf16x8*)(wc16 + (size_t)lane15 * CKK + st * 32 + g8);
    bf16x8 a1  = *(const bf16x8*)(wc16 + (size_t)(16 + lane15) * CKK + st * 32 + g8);

    for (; st < stend; ++st) {
        int stn  = (st + 1 < stend) ? st + 1 : stbeg;
        int tapn = stn / 3;
        int c2n  = ((stn - 3 * tapn) * 32 + g8) * 2;
        bf16x8 bn  = *(const bf16x8*)(pB + sOff[tapn][px_local] + c2n);
        bf16x8 a0n = *(const bf16x8*)(wc16 + (size_t)lane15 * CKK + stn * 32 + g8);
        bf16x8 a1n = *(const bf16x8*)(wc16 + (size_t)(16 + lane15) * CKK + stn * 32 + g8);

        acc[0] = __builtin_amdgcn_mfma_f32_16x16x32_bf16(a0, bfr, acc[0], 0, 0, 0);
        acc[1] = __builtin_amdgcn_mfma_f32_16x16x32_bf16(a1, bfr, acc[1], 0, 0, 0);
        bfr = bn; a0 = a0n; a1 = a1n;
    }

    if (ks == 1) {
#pragma unroll
        for (int i = 0; i < 2; ++i)
#pragma unroll
            for (int r = 0; r < 4; ++r)
                sRed[nt][i * 4 + r][l64] = acc[i][r];
    }
    __syncthreads();
    if (ks == 0) {
        float* ap = aux + (size_t)b * AUXC * HWSZ + y * NW + x0 + px_local;
#pragma unroll
        for (int i = 0; i < 2; ++i) {
#pragma unroll
            for (int r = 0; r < 4; ++r) {
                int oc = i * 16 + g * 4 + r;
                float v = acc[i][r] + sRed[nt][i * 4 + r][l64];
                if (oc < 18) {
                    ap[oc * HWSZ] = v + offb[oc];
                } else if (oc < AUXC) {
                    float z = v + modb[oc - 18];
                    ap[oc * HWSZ] = 2.f / (1.f + __expf(-z));
                }
            }
        }
    }
}

// ---------------------------------------------------------------------------
// Kernel 2: deformable sampling + MFMA, 1-deep prefetch of BOTH samples and
// A-fragments; B-fragment rounding via v_cvt_pk_bf16_f32 (bitwise == bf16r).
// ---------------------------------------------------------------------------
__global__ __launch_bounds__(512, 4) void deform_mfma_kernel(
    const unsigned short* __restrict__ xhwc,
    const float* __restrict__ aux,
    const unsigned short* __restrict__ wb16,
    float* __restrict__ out)
{
    __shared__ uint4 sA[NK][66];
    __shared__ uint2 sW[NK][66];
    __shared__ float sRed[4][24][64];

    int t = threadIdx.x;
    int bid = blockIdx.x;
    int work = ((bid & 7) << 7) | (bid >> 3);
    int base = work * 64;
    int b = base >> 14;
    int rem0 = base & (HWSZ - 1);
    int y = rem0 >> 7;
    int x0 = rem0 & (NW - 1);

    const float* auxb = aux + (size_t)b * AUXC * HWSZ;

    for (int e = t; e < 576; e += 512) {
        int px = e & 63;
        int k  = e >> 6;
        int xcol = x0 + px;
        int idx = y * NW + xcol;
        float offy = auxb[(2 * k) * HWSZ + idx];
        float offx = auxb[(2 * k + 1) * HWSZ + idx];
        float m    = auxb[(18 + k) * HWSZ + idx];
        int ky = k / 3, kx = k - 3 * (k / 3);
        float py  = (float)(y - 1 + ky) + offy;
        float pxf = (float)(xcol - 1 + kx) + offx;
        float y0f = floorf(py), x0f = floorf(pxf);
        float dy = py - y0f, dx = pxf - x0f;
        int iy0 = (int)y0f, ix0 = (int)x0f;
        int iy1 = iy0 + 1,  ix1 = ix0 + 1;

        bool vy0 = (iy0 >= 0) && (iy0 < NH);
        bool vy1 = (iy1 >= 0) && (iy1 < NH);
        bool vx0 = (ix0 >= 0) && (ix0 < NW);
        bool vx1 = (ix1 >= 0) && (ix1 < NW);
        int cy0 = min(max(iy0, 0), NH - 1);
        int cy1 = min(max(iy1, 0), NH - 1);
        int cx0 = min(max(ix0, 0), NW - 1);
        int cx1 = min(max(ix1, 0), NW - 1);

        float g00 = (1.f - dy) * (1.f - dx) * m; if (!(vy0 && vx0)) g00 = 0.f;
        float g01 = (1.f - dy) * dx * m;         if (!(vy0 && vx1)) g01 = 0.f;
        float g10 = dy * (1.f - dx) * m;         if (!(vy1 && vx0)) g10 = 0.f;
        float g11 = dy * dx * m;                 if (!(vy1 && vx1)) g11 = 0.f;

        uint4 ua;
        ua.x = (unsigned int)(cy0 * NW + cx0) * PIXB;
        ua.y = (unsigned int)(cy0 * NW + cx1) * PIXB;
        ua.z = (unsigned int)(cy1 * NW + cx0) * PIXB;
        ua.w = (unsigned int)(cy1 * NW + cx1) * PIXB;
        uint2 uw;
        uw.x = bf16r(g00) | (bf16r(g01) << 16);
        uw.y = bf16r(g10) | (bf16r(g11) << 16);
        sA[k][px] = ua;
        sW[k][px] = uw;
    }
    __syncthreads();

    f32x4 acc[6];
#pragma unroll
    for (int i = 0; i < 6; ++i) acc[i] = (f32x4){0.f, 0.f, 0.f, 0.f};

    const int lane15   = t & 15;
    const int g        = (t >> 4) & 3;
    const int wv       = t >> 6;
    const int nt       = wv & 3;
    const int ks       = wv >> 2;
    const int px_local = (nt << 4) | lane15;
    const int g8       = g << 3;
    const int l64      = t & 63;

    const int stbeg = ks ? 14 : 0;
    const int stend = ks ? 27 : 14;

    const char* pB = (const char*)(xhwc + (size_t)b * HWSZ * NC);

    // prologue: samples + A fragments for stbeg
    int st = stbeg;
    int k_ = st / 3;
    int c2 = ((st - 3 * k_) * 32 + g8) * 2;
    uint4 ga = sA[k_][px_local];
    uint2 gw = sW[k_][px_local];
    bf16x8 v0 = *(const bf16x8*)(pB + ga.x + c2);
    bf16x8 v1 = *(const bf16x8*)(pB + ga.y + c2);
    bf16x8 v2 = *(const bf16x8*)(pB + ga.z + c2);
    bf16x8 v3 = *(const bf16x8*)(pB + ga.w + c2);
    bf16x8 afr[6];
#pragma unroll
    for (int i = 0; i < 6; ++i)
        afr[i] = *(const bf16x8*)(wb16 + (size_t)(i * 16 + lane15) * CKK + st * 32 + g8);

    for (; st < stend; ++st) {
        int stn = (st + 1 < stend) ? st + 1 : stbeg;
        int kn  = stn / 3;
        int c2n = ((stn - 3 * kn) * 32 + g8) * 2;
        uint4 gaN = sA[kn][px_local];
        uint2 gwN = sW[kn][px_local];
        bf16x8 n0 = *(const bf16x8*)(pB + gaN.x + c2n);
        bf16x8 n1 = *(const bf16x8*)(pB + gaN.y + c2n);
        bf16x8 n2 = *(const bf16x8*)(pB + gaN.z + c2n);
        bf16x8 n3 = *(const bf16x8*)(pB + gaN.w + c2n);
        bf16x8 afrN[6];
#pragma unroll
        for (int i = 0; i < 6; ++i)
            afrN[i] = *(const bf16x8*)(wb16 + (size_t)(i * 16 + lane15) * CKK + stn * 32 + g8);

        float w00 = uaf(gw.x << 16), w01 = uaf(gw.x & 0xffff0000u);
        float w10 = uaf(gw.y << 16), w11 = uaf(gw.y & 0xffff0000u);
        float s[8];
#pragma unroll
        for (int j = 0; j < 8; ++j) {
            float f0 = uaf((unsigned int)(unsigned short)v0[j] << 16);
            float f1 = uaf((unsigned int)(unsigned short)v1[j] << 16);
            float f2 = uaf((unsigned int)(unsigned short)v2[j] << 16);
            float f3 = uaf((unsigned int)(unsigned short)v3[j] << 16);
            float sv = f0 * w00;
            sv = fmaf(f1, w01, sv);
            sv = fmaf(f2, w10, sv);
            sv = fmaf(f3, w11, sv);
            s[j] = sv;
        }
        union { bf16x8 h; unsigned int u[4]; } uu;
#pragma unroll
        for (int jj = 0; jj < 4; ++jj)
            uu.u[jj] = cvtpk(s[2 * jj], s[2 * jj + 1]);
        bf16x8 bfr = uu.h;

#pragma unroll
        for (int i = 0; i < 6; ++i)
            acc[i] = __builtin_amdgcn_mfma_f32_16x16x32_bf16(afr[i], bfr, acc[i], 0, 0, 0);

        ga = gaN; gw = gwN; v0 = n0; v1 = n1; v2 = n2; v3 = n3;
#pragma unroll
        for (int i = 0; i < 6; ++i) afr[i] = afrN[i];
    }

    if (ks == 1) {
#pragma unroll
        for (int i = 0; i < 6; ++i)
#pragma unroll
            for (int r = 0; r < 4; ++r)
                sRed[nt][i * 4 + r][l64] = acc[i][r];
    }
    __syncthreads();
    if (ks == 0) {
        float* ob = out + (size_t)b * NC * HWSZ + y * NW + x0 + px_local;
#pragma unroll
        for (int i = 0; i < 6; ++i) {
            int row0 = i * 16 + g * 4;
#pragma unroll
            for (int r = 0; r < 4; ++r)
                ob[(row0 + r) * HWSZ] = acc[i][r] + sRed[nt][i * 4 + r][l64];
        }
    }
}

// ---------------------------------------------------------------------------
// Kernel 3a: per-(b,c) partial sums.  Kernel 3b: finalize scale/shift.
// ---------------------------------------------------------------------------
__global__ __launch_bounds__(256) void bnstats_kernel(
    const float* __restrict__ h, float* __restrict__ part)
{
    int bc = blockIdx.x;
    const float4* p = (const float4*)(h + (size_t)bc * HWSZ);
    float s = 0.f, s2 = 0.f;
    for (int i = threadIdx.x; i < HWSZ / 4; i += 256) {
        float4 v = p[i];
        s  += v.x + v.y + v.z + v.w;
        s2 += v.x * v.x + v.y * v.y + v.z * v.z + v.w * v.w;
    }
#pragma unroll
    for (int o = 32; o > 0; o >>= 1) {
        s  += __shfl_down(s, o);
        s2 += __shfl_down(s2, o);
    }
    __shared__ float red[8];
    int wv = threadIdx.x >> 6, ln = threadIdx.x & 63;
    if (ln == 0) { red[wv] = s; red[4 + wv] = s2; }
    __syncthreads();
    if (threadIdx.x == 0) {
        part[bc]            = red[0] + red[1] + red[2] + red[3];
        part[NB * NC + bc]  = red[4] + red[5] + red[6] + red[7];
    }
}

__global__ __launch_bounds__(128) void bnfinalize_kernel(
    const float* __restrict__ part, const float* __restrict__ g,
    const float* __restrict__ bt, float* __restrict__ sc)
{
    int c = threadIdx.x;
    if (c >= NC) return;
    float s = 0.f, s2 = 0.f;
#pragma unroll
    for (int b = 0; b < NB; ++b) {
        s  += part[b * NC + c];
        s2 += part[NB * NC + b * NC + c];
    }
    const float inv_n = 1.f / (float)(NB * HWSZ);
    float mean = s * inv_n;
    float var  = s2 * inv_n - mean * mean;
    float scale = g[c] * rsqrtf(var + 1e-5f);
    sc[c] = scale;
    sc[NC + c] = bt[c] - mean * scale;
}

// ---------------------------------------------------------------------------
// Kernel 5: out = x + BN(out_raw) in place
// ---------------------------------------------------------------------------
__global__ __launch_bounds__(256) void final_kernel(
    float* __restrict__ out, const float* __restrict__ x,
    const float* __restrict__ sc)
{
    const int n4 = NB * NC * HWSZ / 4;
    for (int i = blockIdx.x * 256 + threadIdx.x; i < n4; i += gridDim.x * 256) {
        int c = (i >> 12) % NC;
        float scale = sc[c], shift = sc[NC + c];
        float4 v = ((const float4*)out)[i];
        float4 xv = ((const float4*)x)[i];
        float4 o;
        o.x = xv.x + fmaf(scale, v.x, shift);
        o.y = xv.y + fmaf(scale, v.y, shift);
        o.z = xv.z + fmaf(scale, v.z, shift);
        o.w = xv.w + fmaf(scale, v.w, shift);
        ((float4*)out)[i] = o;
    }
}

// ---------------------------------------------------------------------------
extern "C" void kernel_launch(void* const* d_in, const int* in_sizes, int n_in,
                              void* d_out, int out_size, void* d_ws, size_t ws_size,
                              hipStream_t stream)
{
    const float* x        = (const float*)d_in[0];
    const float* d1_off_w = (const float*)d_in[1];
    const float* d1_off_b = (const float*)d_in[2];
    const float* d1_mod_w = (const float*)d_in[3];
    const float* d1_mod_b = (const float*)d_in[4];
    const float* d1_w     = (const float*)d_in[5];
    const float* d2_off_w = (const float*)d_in[6];
    const float* d2_off_b = (const float*)d_in[7];
    const float* d2_mod_w = (const float*)d_in[8];
    const float* d2_mod_b = (const float*)d_in[9];
    const float* d2_w     = (const float*)d_in[10];
    const float* bn_g     = (const float*)d_in[11];
    const float* bn_b     = (const float*)d_in[12];
    float* out = (float*)d_out;

    // ws layout (floats): h1 | aux | wc16 | wb16 | sc | part | xhwc(+zero rec)
    const size_t nImg = (size_t)NB * NC * HWSZ;
    float* h1   = (float*)d_ws;
    float* aux  = h1   + nImg;
    unsigned short* wc16 = (unsigned short*)(aux + (size_t)NB * AUXC * HWSZ);
    unsigned short* wb16 = wc16 + WC_ELEMS;
    float* sc   = (float*)(wb16 + WB_ELEMS);
    float* part = sc + 2 * NC;
    unsigned short* xhwc = (unsigned short*)(part + 2 * NB * NC);

    const int npix = NB * HWSZ;                       // 65536
    const int prep_blocks = (WC_ELEMS + WB_ELEMS + 255) / 256;

    // ---- layer 1 ----
    prep_weights_kernel<<<prep_blocks, 256, 0, stream>>>(d1_off_w, d1_mod_w, d1_w, wc16, wb16);
    nhwc_kernel<<<npix / 64, 256, 0, stream>>>(x, xhwc);
    conv27_mfma_kernel<<<npix / 64, 512, 0, stream>>>(xhwc, wc16, d1_off_b, d1_mod_b, aux);
    deform_mfma_kernel<<<npix / 64, 512, 0, stream>>>(xhwc, aux, wb16, h1);
    bnstats_kernel<<<NB * NC, 256, 0, stream>>>(h1, part);
    bnfinalize_kernel<<<1, 128, 0, stream>>>(part, bn_g, bn_b, sc);

    // ---- layer 2 ----
    prep_weights_kernel<<<prep_blocks, 256, 0, stream>>>(d2_off_w, d2_mod_w, d2_w, wc16, wb16);
    nhwcbn_kernel<<<npix / 64, 256, 0, stream>>>(h1, sc, xhwc);
    conv27_mfma_kernel<<<npix / 64, 512, 0, stream>>>(xhwc, wc16, d2_off_b, d2_mod_b, aux);
    deform_mfma_kernel<<<npix / 64, 512, 0, stream>>>(xhwc, aux, wb16, out);
    bnstats_kernel<<<NB * NC, 256, 0, stream>>>(out, part);
    bnfinalize_kernel<<<1, 128, 0, stream>>>(part, bn_g, bn_b, sc);
    final_kernel<<<2048, 256, 0, stream>>>(out, x, sc);
}